// Round 11
// baseline (78.715 us; speedup 1.0000x reference)
//
#include <hip/hip_runtime.h>
#include <math.h>

#define L_SEQ 2048
#define H_CH  512
#define N_ST  64

__device__ __forceinline__ float frcp(float x) { return __builtin_amdgcn_rcpf(x); }
// float2-granular LDS pad for FFT buffers
#define A2(i) ((i) + ((i) >> 4))

// ---------------------------------------------------------------------------
// Radix-2 DIF FFT in LDS. Natural-order input, bit-reversed output.
// tw[A2(k)] = e^{+2pi i k/2048}, k<1024. ssign=-1 -> forward, +1 -> inverse
// (unnormalized). ST0: first stage to execute (ST0=1 when stage 0 was fused
// into the pack step, e.g. zero-padded upper half).
// ---------------------------------------------------------------------------
template<int LOGN, int ST0 = 0>
__device__ __forceinline__ void fft_lds(float2* buf, const float2* tw,
                                        int tid, float ssign)
{
    constexpr int N   = 1 << LOGN;
    constexpr int NBF = N / 512;                 // butterflies/thread/stage
#pragma unroll
    for (int st = ST0; st < LOGN; ++st) {
        const int h2s = (N >> 1) >> st;
#pragma unroll
        for (int bq = 0; bq < NBF; ++bq) {
            const int b  = tid + bq * 256;
            const int j  = b & (h2s - 1);
            const int i0 = ((b >> (LOGN - 1 - st)) << (LOGN - st)) + j;
            const int i1 = i0 + h2s;
            const float2 uu = buf[A2(i0)];
            const float2 vv = buf[A2(i1)];
            const float2 w  = tw[A2((j << st) << (11 - LOGN))];
            const float  wy = ssign * w.y;
            buf[A2(i0)] = make_float2(uu.x + vv.x, uu.y + vv.y);
            const float d0 = uu.x - vv.x, d1 = uu.y - vv.y;
            buf[A2(i1)] = make_float2(d0 * w.x - d1 * wy, d0 * wy + d1 * w.x);
        }
        __syncthreads();
    }
}

// ---------------------------------------------------------------------------
// Kernel 0: precompute per-(h,n) Cauchy weights into global scratch.
// ---------------------------------------------------------------------------
__global__ __launch_bounds__(256)
void s4_prep(const float* __restrict__ lam_r_g, const float* __restrict__ lam_i_g,
             const float* __restrict__ p_r_g,  const float* __restrict__ p_i_g,
             const float* __restrict__ b_r_g,  const float* __restrict__ b_i_g,
             const float* __restrict__ c_g,
             float4* __restrict__ Wa, float4* __restrict__ Wb, float* __restrict__ Wc)
{
    const int g = blockIdx.x * 256 + threadIdx.x;      // [0, 512*64)
    const float lr = fminf(lam_r_g[g], -0.0001f);
    const float li = lam_i_g[g];
    const float pr = p_r_g[g], pi = p_i_g[g];
    const float br = b_r_g[g], bi = b_i_g[g];
    const float c0 = c_g[2 * g], c1 = c_g[2 * g + 1];
    Wa[g] = make_float4(lr, li, c0 * br + c1 * bi, c0 * bi - c1 * br);
    Wb[g] = make_float4(c0 * pr + c1 * pi, c0 * pi - c1 * pr,
                        pr * br + pi * bi, pr * bi - pi * br);
    Wc[g] = pr * pr + pi * pi;
}

// ---------------------------------------------------------------------------
// Kernel 1: Cauchy generating function -> roots[h][l].
// 2 l-points per thread (l, l+256): the block-uniform scalar weight loads
// (s_load, ~180 cyc) now feed 2x the FMA work -> latency hidden (R10: 69%
// VALUBusy was scalar-load stall at 1 point/thread).
// ---------------------------------------------------------------------------
__global__ __launch_bounds__(256)
void s4_cauchy(const float4* __restrict__ Wa, const float4* __restrict__ Wb,
               const float* __restrict__ Wc, const float* __restrict__ log_step_g,
               float2* __restrict__ roots)
{
    const int h  = blockIdx.y;
    const int l0 = blockIdx.x * 512 + threadIdx.x;
    const int l1 = l0 + 256;

    const float step = expf(log_step_g[h]);
    const float ts   = 2.0f / step;

    float wi0, wr0, wi1, wr1;
    sincosf(-6.2831853071795864769f * ((float)l0 * (1.0f / (float)L_SEQ)), &wi0, &wr0);
    sincosf(-6.2831853071795864769f * ((float)l1 * (1.0f / (float)L_SEQ)), &wi1, &wr1);

    const float dr0 = 1.0f + wr0, di0 = wi0;
    const float dv0 = frcp(dr0 * dr0 + di0 * di0);
    const float nr0 = 1.0f - wr0, ni0 = -wi0;
    const float gr0 = ts * (nr0 * dr0 + ni0 * di0) * dv0;
    const float gi0 = ts * (ni0 * dr0 - nr0 * di0) * dv0;
    const float c2r0 = 2.0f * dr0 * dv0, c2i0 = -2.0f * di0 * dv0;

    const float dr1 = 1.0f + wr1, di1 = wi1;
    const float dv1 = frcp(dr1 * dr1 + di1 * di1);
    const float nr1 = 1.0f - wr1, ni1 = -wi1;
    const float gr1 = ts * (nr1 * dr1 + ni1 * di1) * dv1;
    const float gi1 = ts * (ni1 * dr1 - nr1 * di1) * dv1;
    const float c2r1 = 2.0f * dr1 * dv1, c2i1 = -2.0f * di1 * dv1;

    const float4* __restrict__ wa = Wa + h * N_ST;
    const float4* __restrict__ wb = Wb + h * N_ST;
    const float*  __restrict__ wc = Wc + h * N_ST;

    float a00r = 0.f, a00i = 0.f, a01r = 0.f, a01i = 0.f;
    float a10r = 0.f, a10i = 0.f, a11r = 0.f, a11i = 0.f;
    float b00r = 0.f, b00i = 0.f, b01r = 0.f, b01i = 0.f;
    float b10r = 0.f, b10i = 0.f, b11r = 0.f, b11i = 0.f;
#pragma unroll 4
    for (int n = 0; n < N_ST; ++n) {
        const float4 A = wa[n];
        const float4 B = wb[n];
        const float w11 = wc[n];

        float ddr = gr0 - A.x, ddi = gi0 - A.y;
        float rinv = frcp(fmaf(ddr, ddr, ddi * ddi));
        float rr = ddr * rinv, ri = -ddi * rinv;
        a00r = fmaf(A.z, rr, fmaf(-A.w, ri, a00r));
        a00i = fmaf(A.z, ri, fmaf( A.w, rr, a00i));
        a01r = fmaf(B.x, rr, fmaf(-B.y, ri, a01r));
        a01i = fmaf(B.x, ri, fmaf( B.y, rr, a01i));
        a10r = fmaf(B.z, rr, fmaf(-B.w, ri, a10r));
        a10i = fmaf(B.z, ri, fmaf( B.w, rr, a10i));
        a11r = fmaf(w11, rr, a11r);
        a11i = fmaf(w11, ri, a11i);

        ddr = gr1 - A.x;  ddi = gi1 - A.y;
        rinv = frcp(fmaf(ddr, ddr, ddi * ddi));
        rr = ddr * rinv;  ri = -ddi * rinv;
        b00r = fmaf(A.z, rr, fmaf(-A.w, ri, b00r));
        b00i = fmaf(A.z, ri, fmaf( A.w, rr, b00i));
        b01r = fmaf(B.x, rr, fmaf(-B.y, ri, b01r));
        b01i = fmaf(B.x, ri, fmaf( B.y, rr, b01i));
        b10r = fmaf(B.z, rr, fmaf(-B.w, ri, b10r));
        b10i = fmaf(B.z, ri, fmaf( B.w, rr, b10i));
        b11r = fmaf(w11, rr, b11r);
        b11i = fmaf(w11, ri, b11i);
    }

    {
        const float qdr = 1.0f + a11r, qdi = a11i;
        const float qinv = frcp(qdr * qdr + qdi * qdi);
        const float pnr = a01r * a10r - a01i * a10i;
        const float pni = a01r * a10i + a01i * a10r;
        const float qr = (pnr * qdr + pni * qdi) * qinv;
        const float qi = (pni * qdr - pnr * qdi) * qinv;
        const float rr0 = a00r - qr, ri0 = a00i - qi;
        roots[h * L_SEQ + l0] = make_float2(c2r0 * rr0 - c2i0 * ri0,
                                            c2r0 * ri0 + c2i0 * rr0);
    }
    {
        const float qdr = 1.0f + b11r, qdi = b11i;
        const float qinv = frcp(qdr * qdr + qdi * qdi);
        const float pnr = b01r * b10r - b01i * b10i;
        const float pni = b01r * b10i + b01i * b10r;
        const float qr = (pnr * qdr + pni * qdi) * qinv;
        const float qi = (pni * qdr - pnr * qdi) * qinv;
        const float rr0 = b00r - qr, ri0 = b00i - qi;
        roots[h * L_SEQ + l1] = make_float2(c2r1 * rr0 - c2i1 * ri0,
                                            c2r1 * ri0 + c2i1 * rr0);
    }
}

// ---------------------------------------------------------------------------
// Kernel 2: fused spectral convolution, one block per h (R10 structure).
// Forward FFTs fuse stage 0 with the zero-padded pack (ST0=1).
// ---------------------------------------------------------------------------
__global__ __launch_bounds__(256)
void s4_fftconv(const float2* __restrict__ roots, const float* __restrict__ u,
                float* __restrict__ Y)
{
    __shared__ float2 bufK[2175];   // A2(2047)=2174
    __shared__ float2 bufU[2175];
    __shared__ float2 tw[1087];     // A2(1023)=1086
    const int h   = blockIdx.x;
    const int tid = threadIdx.x;
    const float2* __restrict__ r = roots + h * L_SEQ;

    // prefetch u column early (global, strided; consumed in phase 3)
    float uv[8];
#pragma unroll
    for (int q = 0; q < 4; ++q) {
        const int t = tid + q * 256;
        uv[q]     = u[t * H_CH + h];
        uv[q + 4] = u[(t + 1024) * H_CH + h];
    }

    for (int k = tid; k < 1024; k += 256) {
        float sv, cv;
        sincosf((float)k * (6.2831853071795864769f / 2048.0f), &sv, &cv);
        tw[A2(k)] = make_float2(cv, sv);
    }

    // ---- phase 1: half-size irfft pack (R7-proven) + 1024-pt inverse FFT ----
#pragma unroll
    for (int q = 0; q < 4; ++q) {
        const int k = tid + q * 256;
        float zr, zi;
        if (k == 0) {
            const float X0 = r[0].x, XM = r[1024].x;
            zr = X0 + XM;  zi = X0 - XM;
        } else {
            const float2 a  = r[k],        b2 = r[2048 - k];
            const float2 a2 = r[1024 - k], b3 = r[1024 + k];
            const float xkr = 0.5f * (a.x + b2.x),  xki = 0.5f * (a.y - b2.y);
            const float xmr = 0.5f * (a2.x + b3.x), xmi = -0.5f * (a2.y - b3.y);
            const float er = xkr + xmr, ei = xki + xmi;
            const float o_r = xkr - xmr, o_i = xki - xmi;
            float sv, cv;
            sincosf((float)k * (6.2831853071795864769f / 2048.0f), &sv, &cv);
            zr = er - fmaf(cv, o_i,  sv * o_r);
            zi = ei + fmaf(cv, o_r, -sv * o_i);
        }
        bufK[A2(k)] = make_float2(zr, zi);
    }
    __syncthreads();
    fft_lds<10>(bufK, tw, tid, 1.0f);      // z[n] at bufK[A2(brev10(n))]

    // ---- phase 2: v = k0 + i*k1 (scaled), fused stage-0, fwd FFT ----
    float2 v0[4];
#pragma unroll
    for (int q = 0; q < 4; ++q) {
        const int t  = tid + q * 256;      // t in [0,1024)
        const int n0 = t >> 1;
        const float2 za = bufK[A2(__brev(n0) >> 22)];
        const float2 zb = bufK[A2(__brev(512 + n0) >> 22)];
        const float k0v = ((t & 1) ? za.y : za.x) * (1.0f / 2048.0f);
        const float k1v = ((t & 1) ? zb.y : zb.x) * (1.0f / 2048.0f);
        v0[q] = make_float2(k0v, k1v);
    }
    __syncthreads();
#pragma unroll
    for (int q = 0; q < 4; ++q) {
        const int t = tid + q * 256;
        const float2 v = v0[q];
        const float2 w = tw[A2(t)];
        bufK[A2(t)] = v;
        // stage 0 fused (upper half zero): buf[t+1024] = v * conj(w)
        bufK[A2(t + 1024)] = make_float2(fmaf(v.x, w.x,  v.y * w.y),
                                         fmaf(v.y, w.x, -v.x * w.y));
    }
    __syncthreads();
    fft_lds<11, 1>(bufK, tw, tid, -1.0f);  // Zk, bit-rev(11)

    // ---- phase 3: u pack, fused stage-0, fwd FFT ----
#pragma unroll
    for (int q = 0; q < 4; ++q) {
        const int t = tid + q * 256;
        const float2 v = make_float2(uv[q], uv[q + 4]);
        const float2 w = tw[A2(t)];
        bufU[A2(t)] = v;
        bufU[A2(t + 1024)] = make_float2(fmaf(v.x, w.x,  v.y * w.y),
                                         fmaf(v.y, w.x, -v.x * w.y));
    }
    __syncthreads();
    fft_lds<11, 1>(bufU, tw, tid, -1.0f);  // Zu, bit-rev(11)

    // ---- phase 4: Hermitian unpack + pointwise product ----
    float2 R[8];
#pragma unroll
    for (int q = 0; q < 8; ++q) {
        const int m  = tid + q * 256;
        const int mp = (2048 - m) & 2047;
        const int bm = __brev(m)  >> 21;
        const int bp = __brev(mp) >> 21;
        const float2 Zk  = bufK[A2(bm)], Zkp = bufK[A2(bp)];
        const float2 Zu  = bufU[A2(bm)], Zup = bufU[A2(bp)];
        const float F0r = 0.5f * (Zk.x + Zkp.x), F0i = 0.5f * (Zk.y - Zkp.y);
        const float F1r = 0.5f * (Zk.y + Zkp.y), F1i = 0.5f * (Zkp.x - Zk.x);
        const float U0r = 0.5f * (Zu.x + Zup.x), U0i = 0.5f * (Zu.y - Zup.y);
        const float U1r = 0.5f * (Zu.y + Zup.y), U1i = 0.5f * (Zup.x - Zu.x);
        const float Pr = F0r * U0r - F0i * U0i;
        const float Pi = F0r * U0i + F0i * U0r;
        const float Qr = F0r * U1r - F0i * U1i + F1r * U0r - F1i * U0i;
        const float Qi = F0r * U1i + F0i * U1r + F1r * U0i + F1i * U0r;
        R[q] = make_float2(Pr - Qi, Pi + Qr);          // R = P + iQ
    }
    __syncthreads();
#pragma unroll
    for (int q = 0; q < 8; ++q) bufK[A2(tid + q * 256)] = R[q];
    __syncthreads();
    fft_lds<11>(bufK, tw, tid, 1.0f);      // r (unnormalized), bit-rev(11)

    // ---- phase 5: epilogue ----
#pragma unroll
    for (int q = 0; q < 4; ++q) {
        const int t = tid + q * 256;       // t in [0,1024)
        const float2 rl = bufK[A2(__brev(t)        >> 21)];
        const float2 rh = bufK[A2(__brev(t + 1024) >> 21)];
        Y[h * 2048 + t]        = rl.x * (1.0f / 2048.0f);
        Y[h * 2048 + 1024 + t] = (rh.x + rl.y) * (1.0f / 2048.0f);
    }
}

// ---------------------------------------------------------------------------
// Kernel 3: finish = 64x64 LDS transpose + d*u add.
// ---------------------------------------------------------------------------
__global__ __launch_bounds__(256)
void s4_finish(const float* __restrict__ Y, const float* __restrict__ u,
               const float* __restrict__ dvec, float* __restrict__ out)
{
    __shared__ float tile[64][65];
    const int t0   = blockIdx.x * 64;
    const int h0   = blockIdx.y * 64;
    const int lane = threadIdx.x & 63;
    const int rowg = threadIdx.x >> 6;         // 0..3

#pragma unroll
    for (int rr = 0; rr < 16; ++rr) {
        const int hr = rowg * 16 + rr;
        tile[hr][lane] = Y[(h0 + hr) * 2048 + t0 + lane];
    }
    __syncthreads();

    const float dh = dvec[h0 + lane];
#pragma unroll
    for (int rr = 0; rr < 16; ++rr) {
        const int tr = rowg * 16 + rr;
        const int t  = t0 + tr;
        out[t * H_CH + h0 + lane] =
            fmaf(dh, u[t * H_CH + h0 + lane], tile[lane][tr]);
    }
}

// ---------------------------------------------------------------------------
extern "C" void kernel_launch(void* const* d_in, const int* in_sizes, int n_in,
                              void* d_out, int out_size, void* d_ws, size_t ws_size,
                              hipStream_t stream)
{
    const float* u        = (const float*)d_in[0];
    const float* lam_r    = (const float*)d_in[1];
    const float* lam_i    = (const float*)d_in[2];
    const float* p_r      = (const float*)d_in[3];
    const float* p_i      = (const float*)d_in[4];
    const float* b_r      = (const float*)d_in[5];
    const float* b_i      = (const float*)d_in[6];
    const float* cmat     = (const float*)d_in[7];
    const float* dvec     = (const float*)d_in[8];
    const float* log_step = (const float*)d_in[9];
    float* out = (float*)d_out;

    char* ws = (char*)d_ws;
    float2* roots = (float2*)ws;                              // 8 MB @ 0
    float*  Y     = (float*)(ws + (size_t)8 * 1024 * 1024);   // 4 MB @ 8M
    float4* Wa    = (float4*)(ws + (size_t)12 * 1024 * 1024); // 512 KB
    float4* Wb    = (float4*)(ws + (size_t)12 * 1024 * 1024 + 512 * 1024);
    float*  Wc    = (float*) (ws + (size_t)13 * 1024 * 1024); // 128 KB

    s4_prep<<<dim3(H_CH * N_ST / 256), dim3(256), 0, stream>>>(
        lam_r, lam_i, p_r, p_i, b_r, b_i, cmat, Wa, Wb, Wc);
    s4_cauchy<<<dim3(L_SEQ / 512, H_CH), dim3(256), 0, stream>>>(
        Wa, Wb, Wc, log_step, roots);
    s4_fftconv<<<dim3(H_CH), dim3(256), 0, stream>>>(roots, u, Y);
    s4_finish<<<dim3(L_SEQ / 64, H_CH / 64), dim3(256), 0, stream>>>(
        Y, u, dvec, out);
}

// Round 13
// 70.670 us; speedup vs baseline: 1.1138x; 1.1138x over previous
//
#include <hip/hip_runtime.h>
#include <math.h>

#define L_SEQ 2048
#define H_CH  512
#define N_ST  64

__device__ __forceinline__ float frcp(float x) { return __builtin_amdgcn_rcpf(x); }
// float2-granular LDS pad for FFT buffers
#define A2(i) ((i) + ((i) >> 4))

// ---------------------------------------------------------------------------
// Radix-2 DIF FFT in LDS. Natural-order input, bit-reversed output.
// tw[A2(k)] = e^{+2pi i k/2048}, k<1024. ssign=-1 -> forward, +1 -> inverse
// (unnormalized). ST0=1 when stage 0 was fused into the pack step.
// ---------------------------------------------------------------------------
template<int LOGN, int ST0 = 0>
__device__ __forceinline__ void fft_lds(float2* buf, const float2* tw,
                                        int tid, float ssign)
{
    constexpr int N   = 1 << LOGN;
    constexpr int NBF = N / 512;                 // butterflies/thread/stage
#pragma unroll
    for (int st = ST0; st < LOGN; ++st) {
        const int h2s = (N >> 1) >> st;
#pragma unroll
        for (int bq = 0; bq < NBF; ++bq) {
            const int b  = tid + bq * 256;
            const int j  = b & (h2s - 1);
            const int i0 = ((b >> (LOGN - 1 - st)) << (LOGN - st)) + j;
            const int i1 = i0 + h2s;
            const float2 uu = buf[A2(i0)];
            const float2 vv = buf[A2(i1)];
            const float2 w  = tw[A2((j << st) << (11 - LOGN))];
            const float  wy = ssign * w.y;
            buf[A2(i0)] = make_float2(uu.x + vv.x, uu.y + vv.y);
            const float d0 = uu.x - vv.x, d1 = uu.y - vv.y;
            buf[A2(i1)] = make_float2(d0 * w.x - d1 * wy, d0 * wy + d1 * w.x);
        }
        __syncthreads();
    }
}

// ---------------------------------------------------------------------------
// Kernel 0: precompute per-(h,n) Cauchy weights into global scratch.
// ---------------------------------------------------------------------------
__global__ __launch_bounds__(256)
void s4_prep(const float* __restrict__ lam_r_g, const float* __restrict__ lam_i_g,
             const float* __restrict__ p_r_g,  const float* __restrict__ p_i_g,
             const float* __restrict__ b_r_g,  const float* __restrict__ b_i_g,
             const float* __restrict__ c_g,
             float4* __restrict__ Wa, float4* __restrict__ Wb, float* __restrict__ Wc)
{
    const int g = blockIdx.x * 256 + threadIdx.x;      // [0, 512*64)
    const float lr = fminf(lam_r_g[g], -0.0001f);
    const float li = lam_i_g[g];
    const float pr = p_r_g[g], pi = p_i_g[g];
    const float br = b_r_g[g], bi = b_i_g[g];
    const float c0 = c_g[2 * g], c1 = c_g[2 * g + 1];
    Wa[g] = make_float4(lr, li, c0 * br + c1 * bi, c0 * bi - c1 * br);
    Wb[g] = make_float4(c0 * pr + c1 * pi, c0 * pi - c1 * pr,
                        pr * br + pi * bi, pr * bi - pi * br);
    Wc[g] = pr * pr + pi * pi;
}

// ---------------------------------------------------------------------------
// Kernel 1: FUSED cauchy + spectral convolution, one block per h.
//  phase 0: cauchy -> roots[0..2047] in LDS (8 pts/thread, 2 passes of 4)
//  phase 1: half-size irfft pack + 1024-pt inverse FFT  -> kern
//  phase 2: Zk = fft2048(k0 + i*k1) (stage-0 fused with zero-pad)
//  phase 3: Zu = fft2048(u0 + i*u1) (stage-0 fused)
//  phase 4: Hermitian unpack, R = F0*U0 + i(F0*U1 + F1*U0)
//  phase 5: r = ifft2048(R); Y_lo = Re r, Y_hi = Re r[.+1024] + Im r
// ---------------------------------------------------------------------------
__global__ __launch_bounds__(256)
void s4_fftconv(const float4* __restrict__ Wa, const float4* __restrict__ Wb,
                const float* __restrict__ Wc, const float* __restrict__ log_step_g,
                const float* __restrict__ u, float* __restrict__ Y)
{
    __shared__ float2 bufK[2175];   // A2(2047)=2174
    __shared__ float2 bufU[2175];   // first acts as roots scratch (natural idx)
    __shared__ float2 tw[1087];     // A2(1023)=1086
    const int h   = blockIdx.x;
    const int tid = threadIdx.x;
    float2* __restrict__ rbuf = bufU;          // roots[0..2047], natural index

    for (int k = tid; k < 1024; k += 256) {
        float sv, cv;
        sincosf((float)k * (6.2831853071795864769f / 2048.0f), &sv, &cv);
        tw[A2(k)] = make_float2(cv, sv);
    }

    // ---- phase 0: cauchy into LDS ----
    const float step = expf(log_step_g[h]);
    const float ts   = 2.0f / step;
    const float4* __restrict__ wa = Wa + h * N_ST;
    const float4* __restrict__ wb = Wb + h * N_ST;
    const float*  __restrict__ wc = Wc + h * N_ST;

    for (int pass = 0; pass < 2; ++pass) {
        float grq[4], giq[4], c2rq[4], c2iq[4];
#pragma unroll
        for (int q = 0; q < 4; ++q) {
            const int l = tid + q * 256 + pass * 1024;
            float wi, wr;
            sincosf(-6.2831853071795864769f * ((float)l * (1.0f / (float)L_SEQ)),
                    &wi, &wr);
            const float dr = 1.0f + wr, di = wi;
            const float dv = frcp(dr * dr + di * di);
            const float nr = 1.0f - wr, ni = -wi;
            grq[q]  = ts * (nr * dr + ni * di) * dv;
            giq[q]  = ts * (ni * dr - nr * di) * dv;
            c2rq[q] = 2.0f * dr * dv;
            c2iq[q] = -2.0f * di * dv;
        }
        float s00r[4] = {0,0,0,0}, s00i[4] = {0,0,0,0};
        float s01r[4] = {0,0,0,0}, s01i[4] = {0,0,0,0};
        float s10r[4] = {0,0,0,0}, s10i[4] = {0,0,0,0};
        float s11r[4] = {0,0,0,0}, s11i[4] = {0,0,0,0};
#pragma unroll 4
        for (int n = 0; n < N_ST; ++n) {
            const float4 A = wa[n];
            const float4 B = wb[n];
            const float w11 = wc[n];
#pragma unroll
            for (int q = 0; q < 4; ++q) {
                const float ddr = grq[q] - A.x;
                const float ddi = giq[q] - A.y;
                const float rinv = frcp(fmaf(ddr, ddr, ddi * ddi));
                const float rr = ddr * rinv;
                const float ri = -ddi * rinv;
                s00r[q] = fmaf(A.z, rr, fmaf(-A.w, ri, s00r[q]));
                s00i[q] = fmaf(A.z, ri, fmaf( A.w, rr, s00i[q]));
                s01r[q] = fmaf(B.x, rr, fmaf(-B.y, ri, s01r[q]));
                s01i[q] = fmaf(B.x, ri, fmaf( B.y, rr, s01i[q]));
                s10r[q] = fmaf(B.z, rr, fmaf(-B.w, ri, s10r[q]));
                s10i[q] = fmaf(B.z, ri, fmaf( B.w, rr, s10i[q]));
                s11r[q] = fmaf(w11, rr, s11r[q]);
                s11i[q] = fmaf(w11, ri, s11i[q]);
            }
        }
#pragma unroll
        for (int q = 0; q < 4; ++q) {
            const float qdr = 1.0f + s11r[q], qdi = s11i[q];
            const float qinv = frcp(qdr * qdr + qdi * qdi);
            const float pnr = s01r[q] * s10r[q] - s01i[q] * s10i[q];
            const float pni = s01r[q] * s10i[q] + s01i[q] * s10r[q];
            const float qr = (pnr * qdr + pni * qdi) * qinv;
            const float qi = (pni * qdr - pnr * qdi) * qinv;
            const float rr0 = s00r[q] - qr, ri0 = s00i[q] - qi;
            rbuf[tid + q * 256 + pass * 1024] =
                make_float2(c2rq[q] * rr0 - c2iq[q] * ri0,
                            c2rq[q] * ri0 + c2iq[q] * rr0);
        }
    }

    // issue u prefetch (consumed in phase 3; latency hidden by phases 1-2)
    float uv[8];
#pragma unroll
    for (int q = 0; q < 4; ++q) {
        const int t = tid + q * 256;
        uv[q]     = u[t * H_CH + h];
        uv[q + 4] = u[(t + 1024) * H_CH + h];
    }

    __syncthreads();   // roots + tw visible

    // ---- phase 1: half-size irfft pack + 1024-pt inverse FFT ----
#pragma unroll
    for (int q = 0; q < 4; ++q) {
        const int k = tid + q * 256;
        float zr, zi;
        if (k == 0) {
            const float X0 = rbuf[0].x, XM = rbuf[1024].x;
            zr = X0 + XM;  zi = X0 - XM;
        } else {
            const float2 a  = rbuf[k],        b2 = rbuf[2048 - k];
            const float2 a2 = rbuf[1024 - k], b3 = rbuf[1024 + k];
            const float xkr = 0.5f * (a.x + b2.x),  xki = 0.5f * (a.y - b2.y);
            const float xmr = 0.5f * (a2.x + b3.x), xmi = -0.5f * (a2.y - b3.y);
            const float er = xkr + xmr, ei = xki + xmi;
            const float o_r = xkr - xmr, o_i = xki - xmi;
            const float2 w = tw[A2(k)];      // (cos, sin) of +2pi k/2048
            zr = er - fmaf(w.x, o_i,  w.y * o_r);
            zi = ei + fmaf(w.x, o_r, -w.y * o_i);
        }
        bufK[A2(k)] = make_float2(zr, zi);   // note: bufK, rbuf distinct arrays
    }
    __syncthreads();
    fft_lds<10>(bufK, tw, tid, 1.0f);      // z[n] at bufK[A2(brev10(n))]

    // ---- phase 2: v = k0 + i*k1 (scaled), fused stage-0, fwd FFT ----
    float2 v0[4];
#pragma unroll
    for (int q = 0; q < 4; ++q) {
        const int t  = tid + q * 256;      // t in [0,1024)
        const int n0 = t >> 1;
        const float2 za = bufK[A2(__brev(n0) >> 22)];
        const float2 zb = bufK[A2(__brev(512 + n0) >> 22)];
        const float k0v = ((t & 1) ? za.y : za.x) * (1.0f / 2048.0f);
        const float k1v = ((t & 1) ? zb.y : zb.x) * (1.0f / 2048.0f);
        v0[q] = make_float2(k0v, k1v);
    }
    __syncthreads();
#pragma unroll
    for (int q = 0; q < 4; ++q) {
        const int t = tid + q * 256;
        const float2 v = v0[q];
        const float2 w = tw[A2(t)];
        bufK[A2(t)] = v;
        bufK[A2(t + 1024)] = make_float2(fmaf(v.x, w.x,  v.y * w.y),
                                         fmaf(v.y, w.x, -v.x * w.y));
    }
    __syncthreads();
    fft_lds<11, 1>(bufK, tw, tid, -1.0f);  // Zk, bit-rev(11)

    // ---- phase 3: u pack (overwrites dead rbuf), fused stage-0, fwd FFT ----
#pragma unroll
    for (int q = 0; q < 4; ++q) {
        const int t = tid + q * 256;
        const float2 v = make_float2(uv[q], uv[q + 4]);
        const float2 w = tw[A2(t)];
        bufU[A2(t)] = v;
        bufU[A2(t + 1024)] = make_float2(fmaf(v.x, w.x,  v.y * w.y),
                                         fmaf(v.y, w.x, -v.x * w.y));
    }
    __syncthreads();
    fft_lds<11, 1>(bufU, tw, tid, -1.0f);  // Zu, bit-rev(11)

    // ---- phase 4: Hermitian unpack + pointwise product ----
    float2 R[8];
#pragma unroll
    for (int q = 0; q < 8; ++q) {
        const int m  = tid + q * 256;
        const int mp = (2048 - m) & 2047;
        const int bm = __brev(m)  >> 21;
        const int bp = __brev(mp) >> 21;
        const float2 Zk  = bufK[A2(bm)], Zkp = bufK[A2(bp)];
        const float2 Zu  = bufU[A2(bm)], Zup = bufU[A2(bp)];
        const float F0r = 0.5f * (Zk.x + Zkp.x), F0i = 0.5f * (Zk.y - Zkp.y);
        const float F1r = 0.5f * (Zk.y + Zkp.y), F1i = 0.5f * (Zkp.x - Zk.x);
        const float U0r = 0.5f * (Zu.x + Zup.x), U0i = 0.5f * (Zu.y - Zup.y);
        const float U1r = 0.5f * (Zu.y + Zup.y), U1i = 0.5f * (Zup.x - Zu.x);
        const float Pr = F0r * U0r - F0i * U0i;
        const float Pi = F0r * U0i + F0i * U0r;
        const float Qr = F0r * U1r - F0i * U1i + F1r * U0r - F1i * U0i;
        const float Qi = F0r * U1i + F0i * U1r + F1r * U0i + F1i * U0r;
        R[q] = make_float2(Pr - Qi, Pi + Qr);          // R = P + iQ
    }
    __syncthreads();
#pragma unroll
    for (int q = 0; q < 8; ++q) bufK[A2(tid + q * 256)] = R[q];
    __syncthreads();
    fft_lds<11>(bufK, tw, tid, 1.0f);      // r (unnormalized), bit-rev(11)

    // ---- phase 5: epilogue ----
#pragma unroll
    for (int q = 0; q < 4; ++q) {
        const int t = tid + q * 256;       // t in [0,1024)
        const float2 rl = bufK[A2(__brev(t)        >> 21)];
        const float2 rh = bufK[A2(__brev(t + 1024) >> 21)];
        Y[h * 2048 + t]        = rl.x * (1.0f / 2048.0f);
        Y[h * 2048 + 1024 + t] = (rh.x + rl.y) * (1.0f / 2048.0f);
    }
}

// ---------------------------------------------------------------------------
// Kernel 2: finish = 64x64 LDS transpose + d*u add.
// ---------------------------------------------------------------------------
__global__ __launch_bounds__(256)
void s4_finish(const float* __restrict__ Y, const float* __restrict__ u,
               const float* __restrict__ dvec, float* __restrict__ out)
{
    __shared__ float tile[64][65];
    const int t0   = blockIdx.x * 64;
    const int h0   = blockIdx.y * 64;
    const int lane = threadIdx.x & 63;
    const int rowg = threadIdx.x >> 6;         // 0..3

#pragma unroll
    for (int rr = 0; rr < 16; ++rr) {
        const int hr = rowg * 16 + rr;
        tile[hr][lane] = Y[(h0 + hr) * 2048 + t0 + lane];
    }
    __syncthreads();

    const float dh = dvec[h0 + lane];
#pragma unroll
    for (int rr = 0; rr < 16; ++rr) {
        const int tr = rowg * 16 + rr;
        const int t  = t0 + tr;
        out[t * H_CH + h0 + lane] =
            fmaf(dh, u[t * H_CH + h0 + lane], tile[lane][tr]);
    }
}

// ---------------------------------------------------------------------------
extern "C" void kernel_launch(void* const* d_in, const int* in_sizes, int n_in,
                              void* d_out, int out_size, void* d_ws, size_t ws_size,
                              hipStream_t stream)
{
    const float* u        = (const float*)d_in[0];
    const float* lam_r    = (const float*)d_in[1];
    const float* lam_i    = (const float*)d_in[2];
    const float* p_r      = (const float*)d_in[3];
    const float* p_i      = (const float*)d_in[4];
    const float* b_r      = (const float*)d_in[5];
    const float* b_i      = (const float*)d_in[6];
    const float* cmat     = (const float*)d_in[7];
    const float* dvec     = (const float*)d_in[8];
    const float* log_step = (const float*)d_in[9];
    float* out = (float*)d_out;

    char* ws = (char*)d_ws;
    float*  Y     = (float*)(ws + (size_t)8 * 1024 * 1024);   // 4 MB @ 8M
    float4* Wa    = (float4*)(ws + (size_t)12 * 1024 * 1024); // 512 KB
    float4* Wb    = (float4*)(ws + (size_t)12 * 1024 * 1024 + 512 * 1024);
    float*  Wc    = (float*) (ws + (size_t)13 * 1024 * 1024); // 128 KB

    s4_prep<<<dim3(H_CH * N_ST / 256), dim3(256), 0, stream>>>(
        lam_r, lam_i, p_r, p_i, b_r, b_i, cmat, Wa, Wb, Wc);
    s4_fftconv<<<dim3(H_CH), dim3(256), 0, stream>>>(
        Wa, Wb, Wc, log_step, u, Y);
    s4_finish<<<dim3(L_SEQ / 64, H_CH / 64), dim3(256), 0, stream>>>(
        Y, u, dvec, out);
}

// Round 14
// 61.858 us; speedup vs baseline: 1.2725x; 1.1425x over previous
//
#include <hip/hip_runtime.h>
#include <math.h>

#define L_SEQ 2048
#define H_CH  512
#define N_ST  64
#define BLK   512   // threads per fftconv block

__device__ __forceinline__ float frcp(float x) { return __builtin_amdgcn_rcpf(x); }
// float2-granular LDS pad for FFT buffers
#define A2(i) ((i) + ((i) >> 4))

// ---------------------------------------------------------------------------
// Radix-2 DIF FFT in LDS, BLK threads. Natural in, bit-reversed out.
// tw[A2(k)] = e^{+2pi i k/2048}, k<1024. ssign=-1 fwd, +1 inv (unnormalized).
// ST0=1 when stage 0 fused into the pack step.
// ---------------------------------------------------------------------------
template<int LOGN, int ST0 = 0>
__device__ __forceinline__ void fft_lds(float2* buf, const float2* tw,
                                        int tid, float ssign)
{
    constexpr int N   = 1 << LOGN;
    constexpr int NBF = (N / 2) / BLK;           // butterflies/thread/stage
#pragma unroll
    for (int st = ST0; st < LOGN; ++st) {
        const int h2s = (N >> 1) >> st;
#pragma unroll
        for (int bq = 0; bq < NBF; ++bq) {
            const int b  = tid + bq * BLK;
            const int j  = b & (h2s - 1);
            const int i0 = ((b >> (LOGN - 1 - st)) << (LOGN - st)) + j;
            const int i1 = i0 + h2s;
            const float2 uu = buf[A2(i0)];
            const float2 vv = buf[A2(i1)];
            const float2 w  = tw[A2((j << st) << (11 - LOGN))];
            const float  wy = ssign * w.y;
            buf[A2(i0)] = make_float2(uu.x + vv.x, uu.y + vv.y);
            const float d0 = uu.x - vv.x, d1 = uu.y - vv.y;
            buf[A2(i1)] = make_float2(d0 * w.x - d1 * wy, d0 * wy + d1 * w.x);
        }
        __syncthreads();
    }
}

// ---------------------------------------------------------------------------
// Kernel 0: precompute per-(h,n) Cauchy weights into global scratch.
// ---------------------------------------------------------------------------
__global__ __launch_bounds__(256)
void s4_prep(const float* __restrict__ lam_r_g, const float* __restrict__ lam_i_g,
             const float* __restrict__ p_r_g,  const float* __restrict__ p_i_g,
             const float* __restrict__ b_r_g,  const float* __restrict__ b_i_g,
             const float* __restrict__ c_g,
             float4* __restrict__ Wa, float4* __restrict__ Wb, float* __restrict__ Wc)
{
    const int g = blockIdx.x * 256 + threadIdx.x;      // [0, 512*64)
    const float lr = fminf(lam_r_g[g], -0.0001f);
    const float li = lam_i_g[g];
    const float pr = p_r_g[g], pi = p_i_g[g];
    const float br = b_r_g[g], bi = b_i_g[g];
    const float c0 = c_g[2 * g], c1 = c_g[2 * g + 1];
    Wa[g] = make_float4(lr, li, c0 * br + c1 * bi, c0 * bi - c1 * br);
    Wb[g] = make_float4(c0 * pr + c1 * pi, c0 * pi - c1 * pr,
                        pr * br + pi * bi, pr * bi - pi * br);
    Wc[g] = pr * pr + pi * pi;
}

// ---------------------------------------------------------------------------
// Kernel 1: FUSED cauchy + spectral convolution, one block (512 thr) per h.
// Identical math/butterflies to R13 (bitwise-same output); 512 threads double
// resident waves/CU 8 -> 16 (grid of 512 blocks = 2 blocks/CU was the cap).
// ---------------------------------------------------------------------------
__global__ __launch_bounds__(BLK)
void s4_fftconv(const float4* __restrict__ Wa, const float4* __restrict__ Wb,
                const float* __restrict__ Wc, const float* __restrict__ log_step_g,
                const float* __restrict__ u, float* __restrict__ Y)
{
    __shared__ float2 bufK[2175];   // A2(2047)=2174
    __shared__ float2 bufU[2175];   // first acts as roots scratch (natural idx)
    __shared__ float2 tw[1087];     // A2(1023)=1086
    const int h   = blockIdx.x;
    const int tid = threadIdx.x;    // [0, 512)
    float2* __restrict__ rbuf = bufU;          // roots[0..2047], natural index

    // u prefetch first: HBM latency hides under the cauchy FMA phase
    float uv[4];
#pragma unroll
    for (int q = 0; q < 2; ++q) {
        const int t = tid + q * BLK;
        uv[q]     = u[t * H_CH + h];
        uv[q + 2] = u[(t + 1024) * H_CH + h];
    }

#pragma unroll
    for (int q = 0; q < 2; ++q) {
        const int k = tid + q * BLK;
        float sv, cv;
        sincosf((float)k * (6.2831853071795864769f / 2048.0f), &sv, &cv);
        tw[A2(k)] = make_float2(cv, sv);
    }

    // ---- phase 0: cauchy into LDS (4 points/thread, one pass) ----
    const float step = expf(log_step_g[h]);
    const float ts   = 2.0f / step;
    const float4* __restrict__ wa = Wa + h * N_ST;
    const float4* __restrict__ wb = Wb + h * N_ST;
    const float*  __restrict__ wc = Wc + h * N_ST;

    {
        float grq[4], giq[4], c2rq[4], c2iq[4];
#pragma unroll
        for (int q = 0; q < 4; ++q) {
            const int l = tid + q * BLK;
            float wi, wr;
            sincosf(-6.2831853071795864769f * ((float)l * (1.0f / (float)L_SEQ)),
                    &wi, &wr);
            const float dr = 1.0f + wr, di = wi;
            const float dv = frcp(dr * dr + di * di);
            const float nr = 1.0f - wr, ni = -wi;
            grq[q]  = ts * (nr * dr + ni * di) * dv;
            giq[q]  = ts * (ni * dr - nr * di) * dv;
            c2rq[q] = 2.0f * dr * dv;
            c2iq[q] = -2.0f * di * dv;
        }
        float s00r[4] = {0,0,0,0}, s00i[4] = {0,0,0,0};
        float s01r[4] = {0,0,0,0}, s01i[4] = {0,0,0,0};
        float s10r[4] = {0,0,0,0}, s10i[4] = {0,0,0,0};
        float s11r[4] = {0,0,0,0}, s11i[4] = {0,0,0,0};
#pragma unroll 4
        for (int n = 0; n < N_ST; ++n) {
            const float4 A = wa[n];
            const float4 B = wb[n];
            const float w11 = wc[n];
#pragma unroll
            for (int q = 0; q < 4; ++q) {
                const float ddr = grq[q] - A.x;
                const float ddi = giq[q] - A.y;
                const float rinv = frcp(fmaf(ddr, ddr, ddi * ddi));
                const float rr = ddr * rinv;
                const float ri = -ddi * rinv;
                s00r[q] = fmaf(A.z, rr, fmaf(-A.w, ri, s00r[q]));
                s00i[q] = fmaf(A.z, ri, fmaf( A.w, rr, s00i[q]));
                s01r[q] = fmaf(B.x, rr, fmaf(-B.y, ri, s01r[q]));
                s01i[q] = fmaf(B.x, ri, fmaf( B.y, rr, s01i[q]));
                s10r[q] = fmaf(B.z, rr, fmaf(-B.w, ri, s10r[q]));
                s10i[q] = fmaf(B.z, ri, fmaf( B.w, rr, s10i[q]));
                s11r[q] = fmaf(w11, rr, s11r[q]);
                s11i[q] = fmaf(w11, ri, s11i[q]);
            }
        }
#pragma unroll
        for (int q = 0; q < 4; ++q) {
            const float qdr = 1.0f + s11r[q], qdi = s11i[q];
            const float qinv = frcp(qdr * qdr + qdi * qdi);
            const float pnr = s01r[q] * s10r[q] - s01i[q] * s10i[q];
            const float pni = s01r[q] * s10i[q] + s01i[q] * s10r[q];
            const float qr = (pnr * qdr + pni * qdi) * qinv;
            const float qi = (pni * qdr - pnr * qdi) * qinv;
            const float rr0 = s00r[q] - qr, ri0 = s00i[q] - qi;
            rbuf[tid + q * BLK] =
                make_float2(c2rq[q] * rr0 - c2iq[q] * ri0,
                            c2rq[q] * ri0 + c2iq[q] * rr0);
        }
    }

    __syncthreads();   // roots + tw visible

    // ---- phase 1: half-size irfft pack + 1024-pt inverse FFT ----
#pragma unroll
    for (int q = 0; q < 2; ++q) {
        const int k = tid + q * BLK;
        float zr, zi;
        if (k == 0) {
            const float X0 = rbuf[0].x, XM = rbuf[1024].x;
            zr = X0 + XM;  zi = X0 - XM;
        } else {
            const float2 a  = rbuf[k],        b2 = rbuf[2048 - k];
            const float2 a2 = rbuf[1024 - k], b3 = rbuf[1024 + k];
            const float xkr = 0.5f * (a.x + b2.x),  xki = 0.5f * (a.y - b2.y);
            const float xmr = 0.5f * (a2.x + b3.x), xmi = -0.5f * (a2.y - b3.y);
            const float er = xkr + xmr, ei = xki + xmi;
            const float o_r = xkr - xmr, o_i = xki - xmi;
            const float2 w = tw[A2(k)];      // (cos, sin) of +2pi k/2048
            zr = er - fmaf(w.x, o_i,  w.y * o_r);
            zi = ei + fmaf(w.x, o_r, -w.y * o_i);
        }
        bufK[A2(k)] = make_float2(zr, zi);
    }
    __syncthreads();
    fft_lds<10>(bufK, tw, tid, 1.0f);      // z[n] at bufK[A2(brev10(n))]

    // ---- phase 2: v = k0 + i*k1 (scaled), fused stage-0, fwd FFT ----
    float2 v0[2];
#pragma unroll
    for (int q = 0; q < 2; ++q) {
        const int t  = tid + q * BLK;      // t in [0,1024)
        const int n0 = t >> 1;
        const float2 za = bufK[A2(__brev(n0) >> 22)];
        const float2 zb = bufK[A2(__brev(512 + n0) >> 22)];
        const float k0v = ((t & 1) ? za.y : za.x) * (1.0f / 2048.0f);
        const float k1v = ((t & 1) ? zb.y : zb.x) * (1.0f / 2048.0f);
        v0[q] = make_float2(k0v, k1v);
    }
    __syncthreads();
#pragma unroll
    for (int q = 0; q < 2; ++q) {
        const int t = tid + q * BLK;
        const float2 v = v0[q];
        const float2 w = tw[A2(t)];
        bufK[A2(t)] = v;
        bufK[A2(t + 1024)] = make_float2(fmaf(v.x, w.x,  v.y * w.y),
                                         fmaf(v.y, w.x, -v.x * w.y));
    }
    __syncthreads();
    fft_lds<11, 1>(bufK, tw, tid, -1.0f);  // Zk, bit-rev(11)

    // ---- phase 3: u pack (overwrites dead rbuf), fused stage-0, fwd FFT ----
#pragma unroll
    for (int q = 0; q < 2; ++q) {
        const int t = tid + q * BLK;
        const float2 v = make_float2(uv[q], uv[q + 2]);
        const float2 w = tw[A2(t)];
        bufU[A2(t)] = v;
        bufU[A2(t + 1024)] = make_float2(fmaf(v.x, w.x,  v.y * w.y),
                                         fmaf(v.y, w.x, -v.x * w.y));
    }
    __syncthreads();
    fft_lds<11, 1>(bufU, tw, tid, -1.0f);  // Zu, bit-rev(11)

    // ---- phase 4: Hermitian unpack + pointwise product ----
    float2 R[4];
#pragma unroll
    for (int q = 0; q < 4; ++q) {
        const int m  = tid + q * BLK;
        const int mp = (2048 - m) & 2047;
        const int bm = __brev(m)  >> 21;
        const int bp = __brev(mp) >> 21;
        const float2 Zk  = bufK[A2(bm)], Zkp = bufK[A2(bp)];
        const float2 Zu  = bufU[A2(bm)], Zup = bufU[A2(bp)];
        const float F0r = 0.5f * (Zk.x + Zkp.x), F0i = 0.5f * (Zk.y - Zkp.y);
        const float F1r = 0.5f * (Zk.y + Zkp.y), F1i = 0.5f * (Zkp.x - Zk.x);
        const float U0r = 0.5f * (Zu.x + Zup.x), U0i = 0.5f * (Zu.y - Zup.y);
        const float U1r = 0.5f * (Zu.y + Zup.y), U1i = 0.5f * (Zup.x - Zu.x);
        const float Pr = F0r * U0r - F0i * U0i;
        const float Pi = F0r * U0i + F0i * U0r;
        const float Qr = F0r * U1r - F0i * U1i + F1r * U0r - F1i * U0i;
        const float Qi = F0r * U1i + F0i * U1r + F1r * U0i + F1i * U0r;
        R[q] = make_float2(Pr - Qi, Pi + Qr);          // R = P + iQ
    }
    __syncthreads();
#pragma unroll
    for (int q = 0; q < 4; ++q) bufK[A2(tid + q * BLK)] = R[q];
    __syncthreads();
    fft_lds<11>(bufK, tw, tid, 1.0f);      // r (unnormalized), bit-rev(11)

    // ---- phase 5: epilogue ----
#pragma unroll
    for (int q = 0; q < 2; ++q) {
        const int t = tid + q * BLK;       // t in [0,1024)
        const float2 rl = bufK[A2(__brev(t)        >> 21)];
        const float2 rh = bufK[A2(__brev(t + 1024) >> 21)];
        Y[h * 2048 + t]        = rl.x * (1.0f / 2048.0f);
        Y[h * 2048 + 1024 + t] = (rh.x + rl.y) * (1.0f / 2048.0f);
    }
}

// ---------------------------------------------------------------------------
// Kernel 2: finish = 64x64 LDS transpose + d*u add.
// ---------------------------------------------------------------------------
__global__ __launch_bounds__(256)
void s4_finish(const float* __restrict__ Y, const float* __restrict__ u,
               const float* __restrict__ dvec, float* __restrict__ out)
{
    __shared__ float tile[64][65];
    const int t0   = blockIdx.x * 64;
    const int h0   = blockIdx.y * 64;
    const int lane = threadIdx.x & 63;
    const int rowg = threadIdx.x >> 6;         // 0..3

#pragma unroll
    for (int rr = 0; rr < 16; ++rr) {
        const int hr = rowg * 16 + rr;
        tile[hr][lane] = Y[(h0 + hr) * 2048 + t0 + lane];
    }
    __syncthreads();

    const float dh = dvec[h0 + lane];
#pragma unroll
    for (int rr = 0; rr < 16; ++rr) {
        const int tr = rowg * 16 + rr;
        const int t  = t0 + tr;
        out[t * H_CH + h0 + lane] =
            fmaf(dh, u[t * H_CH + h0 + lane], tile[lane][tr]);
    }
}

// ---------------------------------------------------------------------------
extern "C" void kernel_launch(void* const* d_in, const int* in_sizes, int n_in,
                              void* d_out, int out_size, void* d_ws, size_t ws_size,
                              hipStream_t stream)
{
    const float* u        = (const float*)d_in[0];
    const float* lam_r    = (const float*)d_in[1];
    const float* lam_i    = (const float*)d_in[2];
    const float* p_r      = (const float*)d_in[3];
    const float* p_i      = (const float*)d_in[4];
    const float* b_r      = (const float*)d_in[5];
    const float* b_i      = (const float*)d_in[6];
    const float* cmat     = (const float*)d_in[7];
    const float* dvec     = (const float*)d_in[8];
    const float* log_step = (const float*)d_in[9];
    float* out = (float*)d_out;

    char* ws = (char*)d_ws;
    float*  Y     = (float*)(ws + (size_t)8 * 1024 * 1024);   // 4 MB @ 8M
    float4* Wa    = (float4*)(ws + (size_t)12 * 1024 * 1024); // 512 KB
    float4* Wb    = (float4*)(ws + (size_t)12 * 1024 * 1024 + 512 * 1024);
    float*  Wc    = (float*) (ws + (size_t)13 * 1024 * 1024); // 128 KB

    s4_prep<<<dim3(H_CH * N_ST / 256), dim3(256), 0, stream>>>(
        lam_r, lam_i, p_r, p_i, b_r, b_i, cmat, Wa, Wb, Wc);
    s4_fftconv<<<dim3(H_CH), dim3(BLK), 0, stream>>>(
        Wa, Wb, Wc, log_step, u, Y);
    s4_finish<<<dim3(L_SEQ / 64, H_CH / 64), dim3(256), 0, stream>>>(
        Y, u, dvec, out);
}

// Round 15
// 60.423 us; speedup vs baseline: 1.3027x; 1.0237x over previous
//
#include <hip/hip_runtime.h>
#include <math.h>

#define L_SEQ 2048
#define H_CH  512
#define N_ST  64
#define BLK   512   // threads per fftconv block

__device__ __forceinline__ float frcp(float x) { return __builtin_amdgcn_rcpf(x); }
// float2-granular LDS pad for FFT buffers
#define A2(i) ((i) + ((i) >> 4))

// ---------------------------------------------------------------------------
// One radix-2^2 quad butterfly: two DIF stages fused in registers.
// Positions e00,e01,e10,e11 = i0, i0+HQ, i0+H, i0+H+HQ. w1 = W(j<<st),
// w2 = W(j<<(st+1)); the (j+H/2) twiddle of stage st is iS*w1 (exact).
// Placement identical to two radix-2 stages -> bit-reversal consumers unchanged.
// ---------------------------------------------------------------------------
__device__ __forceinline__ void quad_bfly(float2* __restrict__ buf,
                                          const float2 w1, const float2 w2,
                                          float S, int e00, int e01, int e10, int e11)
{
    const float2 u0 = buf[e00], u1 = buf[e01];
    const float2 v0 = buf[e10], v1 = buf[e11];
    const float w1y = S * w1.y, w2y = S * w2.y;
    const float2 A = make_float2(u0.x + v0.x, u0.y + v0.y);
    const float2 C = make_float2(u1.x + v1.x, u1.y + v1.y);
    float dx = u0.x - v0.x, dy = u0.y - v0.y;
    const float2 B  = make_float2(dx * w1.x - dy * w1y, dx * w1y + dy * w1.x);
    dx = u1.x - v1.x;  dy = u1.y - v1.y;
    const float2 Dc = make_float2(dx * w1.x - dy * w1y, dx * w1y + dy * w1.x);
    const float2 D  = make_float2(-S * Dc.y, S * Dc.x);          // * iS
    buf[e00] = make_float2(A.x + C.x, A.y + C.y);
    dx = A.x - C.x;  dy = A.y - C.y;
    buf[e01] = make_float2(dx * w2.x - dy * w2y, dx * w2y + dy * w2.x);
    buf[e10] = make_float2(B.x + D.x, B.y + D.y);
    dx = B.x - D.x;  dy = B.y - D.y;
    buf[e11] = make_float2(dx * w2.x - dy * w2y, dx * w2y + dy * w2.x);
}

// ---------------------------------------------------------------------------
// Radix-2^2 DIF FFT in LDS, BLK threads. Natural in, bit-reversed out
// (identical placement to the radix-2 version). tw[A2(k)] = e^{+2pi i k/2048}.
// ssign=-1 fwd, +1 inv (unnormalized). Lone leading radix-2 stage when
// (LOGN-ST0) is odd.
// ---------------------------------------------------------------------------
template<int LOGN, int ST0 = 0>
__device__ __forceinline__ void fft4_lds(float2* buf, const float2* tw,
                                         int tid, float ssign)
{
    constexpr int N  = 1 << LOGN;
    constexpr int SH = 11 - LOGN;
    int st = ST0;
    if constexpr (((LOGN - ST0) & 1) != 0) {
        const int H = (N >> 1) >> ST0;
        for (int b = tid; b < N / 2; b += BLK) {
            const int j  = b & (H - 1);
            const int i0 = ((b >> (LOGN - 1 - ST0)) << (LOGN - ST0)) + j;
            const int i1 = i0 + H;
            const float2 uu = buf[A2(i0)];
            const float2 vv = buf[A2(i1)];
            const float2 w  = tw[A2((j << ST0) << SH)];
            const float  wy = ssign * w.y;
            buf[A2(i0)] = make_float2(uu.x + vv.x, uu.y + vv.y);
            const float d0 = uu.x - vv.x, d1 = uu.y - vv.y;
            buf[A2(i1)] = make_float2(d0 * w.x - d1 * wy, d0 * wy + d1 * w.x);
        }
        __syncthreads();
        st = ST0 + 1;
    }
    for (; st < LOGN; st += 2) {
        const int H  = (N >> 1) >> st;
        const int HQ = H >> 1;
        for (int q = tid; q < N / 4; q += BLK) {
            const int j   = q & (HQ - 1);
            const int blk = q >> (LOGN - 2 - st);
            const int i0  = (blk << (LOGN - st)) + j;
            quad_bfly(buf,
                      tw[A2((j << st) << SH)],
                      tw[A2((j << (st + 1)) << SH)],
                      ssign,
                      A2(i0), A2(i0 + HQ), A2(i0 + H), A2(i0 + H + HQ));
        }
        __syncthreads();
    }
}

// Dual: run the same stage-pair schedule on TWO buffers under shared syncs
// (K- and U-forward FFTs fused; 2x ILP, half the barriers). LOGN-ST0 even.
template<int LOGN, int ST0>
__device__ __forceinline__ void fft4_lds_dual(float2* bK, float2* bU,
                                              const float2* tw, int tid, float ssign)
{
    constexpr int N  = 1 << LOGN;
    constexpr int SH = 11 - LOGN;
    static_assert(((LOGN - ST0) & 1) == 0, "dual needs even stage count");
    for (int st = ST0; st < LOGN; st += 2) {
        const int H  = (N >> 1) >> st;
        const int HQ = H >> 1;
        for (int q = tid; q < N / 4; q += BLK) {
            const int j   = q & (HQ - 1);
            const int blk = q >> (LOGN - 2 - st);
            const int i0  = (blk << (LOGN - st)) + j;
            const float2 w1 = tw[A2((j << st) << SH)];
            const float2 w2 = tw[A2((j << (st + 1)) << SH)];
            const int e00 = A2(i0), e01 = A2(i0 + HQ);
            const int e10 = A2(i0 + H), e11 = A2(i0 + H + HQ);
            quad_bfly(bK, w1, w2, ssign, e00, e01, e10, e11);
            quad_bfly(bU, w1, w2, ssign, e00, e01, e10, e11);
        }
        __syncthreads();
    }
}

// ---------------------------------------------------------------------------
// Kernel 0: precompute per-(h,n) Cauchy weights into global scratch.
// ---------------------------------------------------------------------------
__global__ __launch_bounds__(256)
void s4_prep(const float* __restrict__ lam_r_g, const float* __restrict__ lam_i_g,
             const float* __restrict__ p_r_g,  const float* __restrict__ p_i_g,
             const float* __restrict__ b_r_g,  const float* __restrict__ b_i_g,
             const float* __restrict__ c_g,
             float4* __restrict__ Wa, float4* __restrict__ Wb, float* __restrict__ Wc)
{
    const int g = blockIdx.x * 256 + threadIdx.x;      // [0, 512*64)
    const float lr = fminf(lam_r_g[g], -0.0001f);
    const float li = lam_i_g[g];
    const float pr = p_r_g[g], pi = p_i_g[g];
    const float br = b_r_g[g], bi = b_i_g[g];
    const float c0 = c_g[2 * g], c1 = c_g[2 * g + 1];
    Wa[g] = make_float4(lr, li, c0 * br + c1 * bi, c0 * bi - c1 * br);
    Wb[g] = make_float4(c0 * pr + c1 * pi, c0 * pi - c1 * pr,
                        pr * br + pi * bi, pr * bi - pi * br);
    Wc[g] = pr * pr + pi * pi;
}

// ---------------------------------------------------------------------------
// Kernel 1: FUSED cauchy + spectral convolution, one block (512 thr) per h.
// Radix-2^2 FFTs: ~22 barriers total (was ~45), FFT LDS traffic halved.
// ---------------------------------------------------------------------------
__global__ __launch_bounds__(BLK)
void s4_fftconv(const float4* __restrict__ Wa, const float4* __restrict__ Wb,
                const float* __restrict__ Wc, const float* __restrict__ log_step_g,
                const float* __restrict__ u, float* __restrict__ Y)
{
    __shared__ float2 bufK[2175];   // A2(2047)=2174
    __shared__ float2 bufU[2175];   // first acts as roots scratch (natural idx)
    __shared__ float2 tw[1087];     // A2(1023)=1086
    const int h   = blockIdx.x;
    const int tid = threadIdx.x;    // [0, 512)
    float2* __restrict__ rbuf = bufU;          // roots[0..2047], natural index

    // u prefetch first: HBM latency hides under the cauchy FMA phase
    float uv[4];
#pragma unroll
    for (int q = 0; q < 2; ++q) {
        const int t = tid + q * BLK;
        uv[q]     = u[t * H_CH + h];
        uv[q + 2] = u[(t + 1024) * H_CH + h];
    }

#pragma unroll
    for (int q = 0; q < 2; ++q) {
        const int k = tid + q * BLK;
        float sv, cv;
        sincosf((float)k * (6.2831853071795864769f / 2048.0f), &sv, &cv);
        tw[A2(k)] = make_float2(cv, sv);
    }

    // ---- phase 0: cauchy into LDS (4 points/thread) ----
    const float step = expf(log_step_g[h]);
    const float ts   = 2.0f / step;
    const float4* __restrict__ wa = Wa + h * N_ST;
    const float4* __restrict__ wb = Wb + h * N_ST;
    const float*  __restrict__ wc = Wc + h * N_ST;

    {
        float grq[4], giq[4], c2rq[4], c2iq[4];
#pragma unroll
        for (int q = 0; q < 4; ++q) {
            const int l = tid + q * BLK;
            float wi, wr;
            sincosf(-6.2831853071795864769f * ((float)l * (1.0f / (float)L_SEQ)),
                    &wi, &wr);
            const float dr = 1.0f + wr, di = wi;
            const float dv = frcp(dr * dr + di * di);
            const float nr = 1.0f - wr, ni = -wi;
            grq[q]  = ts * (nr * dr + ni * di) * dv;
            giq[q]  = ts * (ni * dr - nr * di) * dv;
            c2rq[q] = 2.0f * dr * dv;
            c2iq[q] = -2.0f * di * dv;
        }
        float s00r[4] = {0,0,0,0}, s00i[4] = {0,0,0,0};
        float s01r[4] = {0,0,0,0}, s01i[4] = {0,0,0,0};
        float s10r[4] = {0,0,0,0}, s10i[4] = {0,0,0,0};
        float s11r[4] = {0,0,0,0}, s11i[4] = {0,0,0,0};
#pragma unroll 4
        for (int n = 0; n < N_ST; ++n) {
            const float4 A = wa[n];
            const float4 B = wb[n];
            const float w11 = wc[n];
#pragma unroll
            for (int q = 0; q < 4; ++q) {
                const float ddr = grq[q] - A.x;
                const float ddi = giq[q] - A.y;
                const float rinv = frcp(fmaf(ddr, ddr, ddi * ddi));
                const float rr = ddr * rinv;
                const float ri = -ddi * rinv;
                s00r[q] = fmaf(A.z, rr, fmaf(-A.w, ri, s00r[q]));
                s00i[q] = fmaf(A.z, ri, fmaf( A.w, rr, s00i[q]));
                s01r[q] = fmaf(B.x, rr, fmaf(-B.y, ri, s01r[q]));
                s01i[q] = fmaf(B.x, ri, fmaf( B.y, rr, s01i[q]));
                s10r[q] = fmaf(B.z, rr, fmaf(-B.w, ri, s10r[q]));
                s10i[q] = fmaf(B.z, ri, fmaf( B.w, rr, s10i[q]));
                s11r[q] = fmaf(w11, rr, s11r[q]);
                s11i[q] = fmaf(w11, ri, s11i[q]);
            }
        }
#pragma unroll
        for (int q = 0; q < 4; ++q) {
            const float qdr = 1.0f + s11r[q], qdi = s11i[q];
            const float qinv = frcp(qdr * qdr + qdi * qdi);
            const float pnr = s01r[q] * s10r[q] - s01i[q] * s10i[q];
            const float pni = s01r[q] * s10i[q] + s01i[q] * s10r[q];
            const float qr = (pnr * qdr + pni * qdi) * qinv;
            const float qi = (pni * qdr - pnr * qdi) * qinv;
            const float rr0 = s00r[q] - qr, ri0 = s00i[q] - qi;
            rbuf[tid + q * BLK] =
                make_float2(c2rq[q] * rr0 - c2iq[q] * ri0,
                            c2rq[q] * ri0 + c2iq[q] * rr0);
        }
    }

    __syncthreads();   // roots + tw visible

    // ---- phase 1: half-size irfft pack + 1024-pt inverse FFT ----
#pragma unroll
    for (int q = 0; q < 2; ++q) {
        const int k = tid + q * BLK;
        float zr, zi;
        if (k == 0) {
            const float X0 = rbuf[0].x, XM = rbuf[1024].x;
            zr = X0 + XM;  zi = X0 - XM;
        } else {
            const float2 a  = rbuf[k],        b2 = rbuf[2048 - k];
            const float2 a2 = rbuf[1024 - k], b3 = rbuf[1024 + k];
            const float xkr = 0.5f * (a.x + b2.x),  xki = 0.5f * (a.y - b2.y);
            const float xmr = 0.5f * (a2.x + b3.x), xmi = -0.5f * (a2.y - b3.y);
            const float er = xkr + xmr, ei = xki + xmi;
            const float o_r = xkr - xmr, o_i = xki - xmi;
            const float2 w = tw[A2(k)];      // (cos, sin) of +2pi k/2048
            zr = er - fmaf(w.x, o_i,  w.y * o_r);
            zi = ei + fmaf(w.x, o_r, -w.y * o_i);
        }
        bufK[A2(k)] = make_float2(zr, zi);
    }
    __syncthreads();
    fft4_lds<10>(bufK, tw, tid, 1.0f);     // z[n] at bufK[A2(brev10(n))]

    // ---- phase 2+3: pack K (kern halves) AND U, fused stage-0, dual fwd FFT ----
    float2 v0[2];
#pragma unroll
    for (int q = 0; q < 2; ++q) {
        const int t  = tid + q * BLK;      // t in [0,1024)
        const int n0 = t >> 1;
        const float2 za = bufK[A2(__brev(n0) >> 22)];
        const float2 zb = bufK[A2(__brev(512 + n0) >> 22)];
        const float k0v = ((t & 1) ? za.y : za.x) * (1.0f / 2048.0f);
        const float k1v = ((t & 1) ? zb.y : zb.x) * (1.0f / 2048.0f);
        v0[q] = make_float2(k0v, k1v);
    }
    __syncthreads();
#pragma unroll
    for (int q = 0; q < 2; ++q) {
        const int t = tid + q * BLK;
        const float2 w = tw[A2(t)];
        const float2 vk = v0[q];
        bufK[A2(t)] = vk;
        bufK[A2(t + 1024)] = make_float2(fmaf(vk.x, w.x,  vk.y * w.y),
                                         fmaf(vk.y, w.x, -vk.x * w.y));
        const float2 vu = make_float2(uv[q], uv[q + 2]);
        bufU[A2(t)] = vu;
        bufU[A2(t + 1024)] = make_float2(fmaf(vu.x, w.x,  vu.y * w.y),
                                         fmaf(vu.y, w.x, -vu.x * w.y));
    }
    __syncthreads();
    fft4_lds_dual<11, 1>(bufK, bufU, tw, tid, -1.0f);   // Zk, Zu (bit-rev 11)

    // ---- phase 4: Hermitian unpack + pointwise product ----
    float2 R[4];
#pragma unroll
    for (int q = 0; q < 4; ++q) {
        const int m  = tid + q * BLK;
        const int mp = (2048 - m) & 2047;
        const int bm = __brev(m)  >> 21;
        const int bp = __brev(mp) >> 21;
        const float2 Zk  = bufK[A2(bm)], Zkp = bufK[A2(bp)];
        const float2 Zu  = bufU[A2(bm)], Zup = bufU[A2(bp)];
        const float F0r = 0.5f * (Zk.x + Zkp.x), F0i = 0.5f * (Zk.y - Zkp.y);
        const float F1r = 0.5f * (Zk.y + Zkp.y), F1i = 0.5f * (Zkp.x - Zk.x);
        const float U0r = 0.5f * (Zu.x + Zup.x), U0i = 0.5f * (Zu.y - Zup.y);
        const float U1r = 0.5f * (Zu.y + Zup.y), U1i = 0.5f * (Zup.x - Zu.x);
        const float Pr = F0r * U0r - F0i * U0i;
        const float Pi = F0r * U0i + F0i * U0r;
        const float Qr = F0r * U1r - F0i * U1i + F1r * U0r - F1i * U0i;
        const float Qi = F0r * U1i + F0i * U1r + F1r * U0i + F1i * U0r;
        R[q] = make_float2(Pr - Qi, Pi + Qr);          // R = P + iQ
    }
    __syncthreads();
#pragma unroll
    for (int q = 0; q < 4; ++q) bufK[A2(tid + q * BLK)] = R[q];
    __syncthreads();
    fft4_lds<11>(bufK, tw, tid, 1.0f);     // r (unnormalized), bit-rev(11)

    // ---- phase 5: epilogue ----
#pragma unroll
    for (int q = 0; q < 2; ++q) {
        const int t = tid + q * BLK;       // t in [0,1024)
        const float2 rl = bufK[A2(__brev(t)        >> 21)];
        const float2 rh = bufK[A2(__brev(t + 1024) >> 21)];
        Y[h * 2048 + t]        = rl.x * (1.0f / 2048.0f);
        Y[h * 2048 + 1024 + t] = (rh.x + rl.y) * (1.0f / 2048.0f);
    }
}

// ---------------------------------------------------------------------------
// Kernel 2: finish = 64x64 LDS transpose + d*u add.
// ---------------------------------------------------------------------------
__global__ __launch_bounds__(256)
void s4_finish(const float* __restrict__ Y, const float* __restrict__ u,
               const float* __restrict__ dvec, float* __restrict__ out)
{
    __shared__ float tile[64][65];
    const int t0   = blockIdx.x * 64;
    const int h0   = blockIdx.y * 64;
    const int lane = threadIdx.x & 63;
    const int rowg = threadIdx.x >> 6;         // 0..3

#pragma unroll
    for (int rr = 0; rr < 16; ++rr) {
        const int hr = rowg * 16 + rr;
        tile[hr][lane] = Y[(h0 + hr) * 2048 + t0 + lane];
    }
    __syncthreads();

    const float dh = dvec[h0 + lane];
#pragma unroll
    for (int rr = 0; rr < 16; ++rr) {
        const int tr = rowg * 16 + rr;
        const int t  = t0 + tr;
        out[t * H_CH + h0 + lane] =
            fmaf(dh, u[t * H_CH + h0 + lane], tile[lane][tr]);
    }
}

// ---------------------------------------------------------------------------
extern "C" void kernel_launch(void* const* d_in, const int* in_sizes, int n_in,
                              void* d_out, int out_size, void* d_ws, size_t ws_size,
                              hipStream_t stream)
{
    const float* u        = (const float*)d_in[0];
    const float* lam_r    = (const float*)d_in[1];
    const float* lam_i    = (const float*)d_in[2];
    const float* p_r      = (const float*)d_in[3];
    const float* p_i      = (const float*)d_in[4];
    const float* b_r      = (const float*)d_in[5];
    const float* b_i      = (const float*)d_in[6];
    const float* cmat     = (const float*)d_in[7];
    const float* dvec     = (const float*)d_in[8];
    const float* log_step = (const float*)d_in[9];
    float* out = (float*)d_out;

    char* ws = (char*)d_ws;
    float*  Y     = (float*)(ws + (size_t)8 * 1024 * 1024);   // 4 MB @ 8M
    float4* Wa    = (float4*)(ws + (size_t)12 * 1024 * 1024); // 512 KB
    float4* Wb    = (float4*)(ws + (size_t)12 * 1024 * 1024 + 512 * 1024);
    float*  Wc    = (float*) (ws + (size_t)13 * 1024 * 1024); // 128 KB

    s4_prep<<<dim3(H_CH * N_ST / 256), dim3(256), 0, stream>>>(
        lam_r, lam_i, p_r, p_i, b_r, b_i, cmat, Wa, Wb, Wc);
    s4_fftconv<<<dim3(H_CH), dim3(BLK), 0, stream>>>(
        Wa, Wb, Wc, log_step, u, Y);
    s4_finish<<<dim3(L_SEQ / 64, H_CH / 64), dim3(256), 0, stream>>>(
        Y, u, dvec, out);
}

// Round 17
// 58.145 us; speedup vs baseline: 1.3538x; 1.0392x over previous
//
#include <hip/hip_runtime.h>
#include <math.h>

#define L_SEQ 2048
#define H_CH  512
#define N_ST  64
#define BLK   1024  // threads per fftconv block (2 blocks/CU = 32 waves/CU)

__device__ __forceinline__ float frcp(float x) { return __builtin_amdgcn_rcpf(x); }
// float2-granular LDS pad for FFT buffers
#define A2(i) ((i) + ((i) >> 4))

// ---------------------------------------------------------------------------
// One radix-2^2 quad butterfly: two DIF stages fused in registers.
// Placement identical to two radix-2 stages -> bit-reversal consumers unchanged.
// ---------------------------------------------------------------------------
__device__ __forceinline__ void quad_bfly(float2* __restrict__ buf,
                                          const float2 w1, const float2 w2,
                                          float S, int e00, int e01, int e10, int e11)
{
    const float2 u0 = buf[e00], u1 = buf[e01];
    const float2 v0 = buf[e10], v1 = buf[e11];
    const float w1y = S * w1.y, w2y = S * w2.y;
    const float2 A = make_float2(u0.x + v0.x, u0.y + v0.y);
    const float2 C = make_float2(u1.x + v1.x, u1.y + v1.y);
    float dx = u0.x - v0.x, dy = u0.y - v0.y;
    const float2 B  = make_float2(dx * w1.x - dy * w1y, dx * w1y + dy * w1.x);
    dx = u1.x - v1.x;  dy = u1.y - v1.y;
    const float2 Dc = make_float2(dx * w1.x - dy * w1y, dx * w1y + dy * w1.x);
    const float2 D  = make_float2(-S * Dc.y, S * Dc.x);          // * iS
    buf[e00] = make_float2(A.x + C.x, A.y + C.y);
    dx = A.x - C.x;  dy = A.y - C.y;
    buf[e01] = make_float2(dx * w2.x - dy * w2y, dx * w2y + dy * w2.x);
    buf[e10] = make_float2(B.x + D.x, B.y + D.y);
    dx = B.x - D.x;  dy = B.y - D.y;
    buf[e11] = make_float2(dx * w2.x - dy * w2y, dx * w2y + dy * w2.x);
}

// ---------------------------------------------------------------------------
// Radix-2^2 DIF FFT in LDS, BLK threads. Natural in, bit-reversed out.
// tw[A2(k)] = e^{+2pi i k/2048}. ssign=-1 fwd, +1 inv (unnormalized).
// Lone leading radix-2 stage when (LOGN-ST0) is odd.
// ---------------------------------------------------------------------------
template<int LOGN, int ST0 = 0>
__device__ __forceinline__ void fft4_lds(float2* buf, const float2* tw,
                                         int tid, float ssign)
{
    constexpr int N  = 1 << LOGN;
    constexpr int SH = 11 - LOGN;
    int st = ST0;
    if constexpr (((LOGN - ST0) & 1) != 0) {
        const int H = (N >> 1) >> ST0;
        for (int b = tid; b < N / 2; b += BLK) {
            const int j  = b & (H - 1);
            const int i0 = ((b >> (LOGN - 1 - ST0)) << (LOGN - ST0)) + j;
            const int i1 = i0 + H;
            const float2 uu = buf[A2(i0)];
            const float2 vv = buf[A2(i1)];
            const float2 w  = tw[A2((j << ST0) << SH)];
            const float  wy = ssign * w.y;
            buf[A2(i0)] = make_float2(uu.x + vv.x, uu.y + vv.y);
            const float d0 = uu.x - vv.x, d1 = uu.y - vv.y;
            buf[A2(i1)] = make_float2(d0 * w.x - d1 * wy, d0 * wy + d1 * w.x);
        }
        __syncthreads();
        st = ST0 + 1;
    }
    for (; st < LOGN; st += 2) {
        const int H  = (N >> 1) >> st;
        const int HQ = H >> 1;
        for (int q = tid; q < N / 4; q += BLK) {
            const int j   = q & (HQ - 1);
            const int blk = q >> (LOGN - 2 - st);
            const int i0  = (blk << (LOGN - st)) + j;
            quad_bfly(buf,
                      tw[A2((j << st) << SH)],
                      tw[A2((j << (st + 1)) << SH)],
                      ssign,
                      A2(i0), A2(i0 + HQ), A2(i0 + H), A2(i0 + H + HQ));
        }
        __syncthreads();
    }
}

// Dual: K- and U-forward FFTs under shared syncs, split across the thread
// space (tid<512 -> K quads, tid>=512 -> U quads): all threads active, per-
// stage critical path halved vs per-thread dual. Requires BLK == N/2.
template<int LOGN, int ST0>
__device__ __forceinline__ void fft4_lds_dual(float2* bK, float2* bU,
                                              const float2* tw, int tid, float ssign)
{
    constexpr int N  = 1 << LOGN;
    constexpr int SH = 11 - LOGN;
    constexpr int NQ = N / 4;
    static_assert(((LOGN - ST0) & 1) == 0, "dual needs even stage count");
    static_assert(BLK == N / 2, "dual split needs BLK == N/2");
    float2* bb = (tid < NQ) ? bK : bU;     // wave-uniform (512 = 8 waves)
    const int q = tid & (NQ - 1);
    for (int st = ST0; st < LOGN; st += 2) {
        const int H  = (N >> 1) >> st;
        const int HQ = H >> 1;
        const int j   = q & (HQ - 1);
        const int blk = q >> (LOGN - 2 - st);
        const int i0  = (blk << (LOGN - st)) + j;
        quad_bfly(bb,
                  tw[A2((j << st) << SH)],
                  tw[A2((j << (st + 1)) << SH)],
                  ssign,
                  A2(i0), A2(i0 + HQ), A2(i0 + H), A2(i0 + H + HQ));
        __syncthreads();
    }
}

// ---------------------------------------------------------------------------
// Kernel 0: precompute per-(h,n) Cauchy weights into global scratch.
// ---------------------------------------------------------------------------
__global__ __launch_bounds__(256)
void s4_prep(const float* __restrict__ lam_r_g, const float* __restrict__ lam_i_g,
             const float* __restrict__ p_r_g,  const float* __restrict__ p_i_g,
             const float* __restrict__ b_r_g,  const float* __restrict__ b_i_g,
             const float* __restrict__ c_g,
             float4* __restrict__ Wa, float4* __restrict__ Wb, float* __restrict__ Wc)
{
    const int g = blockIdx.x * 256 + threadIdx.x;      // [0, 512*64)
    const float lr = fminf(lam_r_g[g], -0.0001f);
    const float li = lam_i_g[g];
    const float pr = p_r_g[g], pi = p_i_g[g];
    const float br = b_r_g[g], bi = b_i_g[g];
    const float c0 = c_g[2 * g], c1 = c_g[2 * g + 1];
    Wa[g] = make_float4(lr, li, c0 * br + c1 * bi, c0 * bi - c1 * br);
    Wb[g] = make_float4(c0 * pr + c1 * pi, c0 * pi - c1 * pr,
                        pr * br + pi * bi, pr * bi - pi * br);
    Wc[g] = pr * pr + pi * pi;
}

// ---------------------------------------------------------------------------
// Kernel 1: FUSED cauchy + spectral convolution, one block (1024 thr) per h.
// Same math/placement as R15 (bitwise-same output); 1024 threads double
// occupancy ceiling to 32 waves/CU so barriers are covered.
// ---------------------------------------------------------------------------
__global__ __launch_bounds__(BLK, 8)
void s4_fftconv(const float4* __restrict__ Wa, const float4* __restrict__ Wb,
                const float* __restrict__ Wc, const float* __restrict__ log_step_g,
                const float* __restrict__ u, float* __restrict__ Y)
{
    __shared__ float2 bufK[2175];   // A2(2047)=2174
    __shared__ float2 bufU[2175];   // first acts as roots scratch (natural idx)
    __shared__ float2 tw[1087];     // A2(1023)=1086
    const int h   = blockIdx.x;
    const int tid = threadIdx.x;    // [0, 1024)
    float2* __restrict__ rbuf = bufU;          // roots[0..2047], natural index

    // u prefetch first: HBM latency hides under the cauchy FMA phase
    const float uv0 = u[tid * H_CH + h];
    const float uv1 = u[(tid + 1024) * H_CH + h];

    {
        float sv, cv;
        sincosf((float)tid * (6.2831853071795864769f / 2048.0f), &sv, &cv);
        tw[A2(tid)] = make_float2(cv, sv);
    }

    // ---- phase 0: cauchy into LDS (2 points/thread: l = tid, tid+1024) ----
    const float step = expf(log_step_g[h]);
    const float ts   = 2.0f / step;
    const float4* __restrict__ wa = Wa + h * N_ST;
    const float4* __restrict__ wb = Wb + h * N_ST;
    const float*  __restrict__ wc = Wc + h * N_ST;

    {
        float grq[2], giq[2], c2rq[2], c2iq[2];
#pragma unroll
        for (int q = 0; q < 2; ++q) {
            const int l = tid + q * BLK;
            float wi, wr;
            sincosf(-6.2831853071795864769f * ((float)l * (1.0f / (float)L_SEQ)),
                    &wi, &wr);
            const float dr = 1.0f + wr, di = wi;
            const float dv = frcp(dr * dr + di * di);
            const float nr = 1.0f - wr, ni = -wi;
            grq[q]  = ts * (nr * dr + ni * di) * dv;
            giq[q]  = ts * (ni * dr - nr * di) * dv;
            c2rq[q] = 2.0f * dr * dv;
            c2iq[q] = -2.0f * di * dv;
        }
        float s00r[2] = {0,0}, s00i[2] = {0,0};
        float s01r[2] = {0,0}, s01i[2] = {0,0};
        float s10r[2] = {0,0}, s10i[2] = {0,0};
        float s11r[2] = {0,0}, s11i[2] = {0,0};
#pragma unroll 4
        for (int n = 0; n < N_ST; ++n) {
            const float4 A = wa[n];
            const float4 B = wb[n];
            const float w11 = wc[n];
#pragma unroll
            for (int q = 0; q < 2; ++q) {
                const float ddr = grq[q] - A.x;
                const float ddi = giq[q] - A.y;
                const float rinv = frcp(fmaf(ddr, ddr, ddi * ddi));
                const float rr = ddr * rinv;
                const float ri = -ddi * rinv;
                s00r[q] = fmaf(A.z, rr, fmaf(-A.w, ri, s00r[q]));
                s00i[q] = fmaf(A.z, ri, fmaf( A.w, rr, s00i[q]));
                s01r[q] = fmaf(B.x, rr, fmaf(-B.y, ri, s01r[q]));
                s01i[q] = fmaf(B.x, ri, fmaf( B.y, rr, s01i[q]));
                s10r[q] = fmaf(B.z, rr, fmaf(-B.w, ri, s10r[q]));
                s10i[q] = fmaf(B.z, ri, fmaf( B.w, rr, s10i[q]));
                s11r[q] = fmaf(w11, rr, s11r[q]);
                s11i[q] = fmaf(w11, ri, s11i[q]);
            }
        }
#pragma unroll
        for (int q = 0; q < 2; ++q) {
            const float qdr = 1.0f + s11r[q], qdi = s11i[q];
            const float qinv = frcp(qdr * qdr + qdi * qdi);
            const float pnr = s01r[q] * s10r[q] - s01i[q] * s10i[q];
            const float pni = s01r[q] * s10i[q] + s01i[q] * s10r[q];
            const float qr = (pnr * qdr + pni * qdi) * qinv;
            const float qi = (pni * qdr - pnr * qdi) * qinv;
            const float rr0 = s00r[q] - qr, ri0 = s00i[q] - qi;
            rbuf[tid + q * BLK] =
                make_float2(c2rq[q] * rr0 - c2iq[q] * ri0,
                            c2rq[q] * ri0 + c2iq[q] * rr0);
        }
    }

    __syncthreads();   // roots + tw visible

    // ---- phase 1: half-size irfft pack + 1024-pt inverse FFT ----
    {
        const int k = tid;              // [0,1024)
        float zr, zi;
        if (k == 0) {
            const float X0 = rbuf[0].x, XM = rbuf[1024].x;
            zr = X0 + XM;  zi = X0 - XM;
        } else {
            const float2 a  = rbuf[k],        b2 = rbuf[2048 - k];
            const float2 a2 = rbuf[1024 - k], b3 = rbuf[1024 + k];
            const float xkr = 0.5f * (a.x + b2.x),  xki = 0.5f * (a.y - b2.y);
            const float xmr = 0.5f * (a2.x + b3.x), xmi = -0.5f * (a2.y - b3.y);
            const float er = xkr + xmr, ei = xki + xmi;
            const float o_r = xkr - xmr, o_i = xki - xmi;
            const float2 w = tw[A2(k)];      // (cos, sin) of +2pi k/2048
            zr = er - fmaf(w.x, o_i,  w.y * o_r);
            zi = ei + fmaf(w.x, o_r, -w.y * o_i);
        }
        bufK[A2(k)] = make_float2(zr, zi);
    }
    __syncthreads();
    fft4_lds<10>(bufK, tw, tid, 1.0f);     // z[n] at bufK[A2(brev10(n))]

    // ---- phase 2+3: pack K (kern halves) AND U, fused stage-0, dual fwd FFT ----
    float2 vk;
    {
        const int t  = tid;             // [0,1024)
        const int n0 = t >> 1;
        const float2 za = bufK[A2(__brev(n0) >> 22)];
        const float2 zb = bufK[A2(__brev(512 + n0) >> 22)];
        const float k0v = ((t & 1) ? za.y : za.x) * (1.0f / 2048.0f);
        const float k1v = ((t & 1) ? zb.y : zb.x) * (1.0f / 2048.0f);
        vk = make_float2(k0v, k1v);
    }
    __syncthreads();
    {
        const int t = tid;
        const float2 w = tw[A2(t)];
        bufK[A2(t)] = vk;
        bufK[A2(t + 1024)] = make_float2(fmaf(vk.x, w.x,  vk.y * w.y),
                                         fmaf(vk.y, w.x, -vk.x * w.y));
        const float2 vu = make_float2(uv0, uv1);
        bufU[A2(t)] = vu;
        bufU[A2(t + 1024)] = make_float2(fmaf(vu.x, w.x,  vu.y * w.y),
                                         fmaf(vu.y, w.x, -vu.x * w.y));
    }
    __syncthreads();
    fft4_lds_dual<11, 1>(bufK, bufU, tw, tid, -1.0f);   // Zk, Zu (bit-rev 11)

    // ---- phase 4: Hermitian unpack + pointwise product (2 bins/thread) ----
    float2 R[2];
#pragma unroll
    for (int q = 0; q < 2; ++q) {
        const int m  = tid + q * BLK;
        const int mp = (2048 - m) & 2047;
        const int bm = __brev(m)  >> 21;
        const int bp = __brev(mp) >> 21;
        const float2 Zk  = bufK[A2(bm)], Zkp = bufK[A2(bp)];
        const float2 Zu  = bufU[A2(bm)], Zup = bufU[A2(bp)];
        const float F0r = 0.5f * (Zk.x + Zkp.x), F0i = 0.5f * (Zk.y - Zkp.y);
        const float F1r = 0.5f * (Zk.y + Zkp.y), F1i = 0.5f * (Zkp.x - Zk.x);
        const float U0r = 0.5f * (Zu.x + Zup.x), U0i = 0.5f * (Zu.y - Zup.y);
        const float U1r = 0.5f * (Zu.y + Zup.y), U1i = 0.5f * (Zup.x - Zu.x);
        const float Pr = F0r * U0r - F0i * U0i;
        const float Pi = F0r * U0i + F0i * U0r;
        const float Qr = F0r * U1r - F0i * U1i + F1r * U0r - F1i * U0i;
        const float Qi = F0r * U1i + F0i * U1r + F1r * U0i + F1i * U0r;
        R[q] = make_float2(Pr - Qi, Pi + Qr);          // R = P + iQ
    }
    __syncthreads();
#pragma unroll
    for (int q = 0; q < 2; ++q) bufK[A2(tid + q * BLK)] = R[q];
    __syncthreads();
    fft4_lds<11>(bufK, tw, tid, 1.0f);     // r (unnormalized), bit-rev(11)

    // ---- phase 5: epilogue ----
    {
        const int t = tid;              // [0,1024)
        const float2 rl = bufK[A2(__brev(t)        >> 21)];
        const float2 rh = bufK[A2(__brev(t + 1024) >> 21)];
        Y[h * 2048 + t]        = rl.x * (1.0f / 2048.0f);
        Y[h * 2048 + 1024 + t] = (rh.x + rl.y) * (1.0f / 2048.0f);
    }
}

// ---------------------------------------------------------------------------
// Kernel 2: finish = 64x64 LDS transpose + d*u add.
// ---------------------------------------------------------------------------
__global__ __launch_bounds__(256)
void s4_finish(const float* __restrict__ Y, const float* __restrict__ u,
               const float* __restrict__ dvec, float* __restrict__ out)
{
    __shared__ float tile[64][65];
    const int t0   = blockIdx.x * 64;
    const int h0   = blockIdx.y * 64;
    const int lane = threadIdx.x & 63;
    const int rowg = threadIdx.x >> 6;         // 0..3

#pragma unroll
    for (int rr = 0; rr < 16; ++rr) {
        const int hr = rowg * 16 + rr;
        tile[hr][lane] = Y[(h0 + hr) * 2048 + t0 + lane];
    }
    __syncthreads();

    const float dh = dvec[h0 + lane];
#pragma unroll
    for (int rr = 0; rr < 16; ++rr) {
        const int tr = rowg * 16 + rr;
        const int t  = t0 + tr;
        out[t * H_CH + h0 + lane] =
            fmaf(dh, u[t * H_CH + h0 + lane], tile[lane][tr]);
    }
}

// ---------------------------------------------------------------------------
extern "C" void kernel_launch(void* const* d_in, const int* in_sizes, int n_in,
                              void* d_out, int out_size, void* d_ws, size_t ws_size,
                              hipStream_t stream)
{
    const float* u        = (const float*)d_in[0];
    const float* lam_r    = (const float*)d_in[1];
    const float* lam_i    = (const float*)d_in[2];
    const float* p_r      = (const float*)d_in[3];
    const float* p_i      = (const float*)d_in[4];
    const float* b_r      = (const float*)d_in[5];
    const float* b_i      = (const float*)d_in[6];
    const float* cmat     = (const float*)d_in[7];
    const float* dvec     = (const float*)d_in[8];
    const float* log_step = (const float*)d_in[9];
    float* out = (float*)d_out;

    char* ws = (char*)d_ws;
    float*  Y     = (float*)(ws + (size_t)8 * 1024 * 1024);   // 4 MB @ 8M
    float4* Wa    = (float4*)(ws + (size_t)12 * 1024 * 1024); // 512 KB
    float4* Wb    = (float4*)(ws + (size_t)12 * 1024 * 1024 + 512 * 1024);
    float*  Wc    = (float*) (ws + (size_t)13 * 1024 * 1024); // 128 KB

    s4_prep<<<dim3(H_CH * N_ST / 256), dim3(256), 0, stream>>>(
        lam_r, lam_i, p_r, p_i, b_r, b_i, cmat, Wa, Wb, Wc);
    s4_fftconv<<<dim3(H_CH), dim3(BLK), 0, stream>>>(
        Wa, Wb, Wc, log_step, u, Y);
    s4_finish<<<dim3(L_SEQ / 64, H_CH / 64), dim3(256), 0, stream>>>(
        Y, u, dvec, out);
}

// Round 18
// 57.633 us; speedup vs baseline: 1.3658x; 1.0089x over previous
//
#include <hip/hip_runtime.h>
#include <math.h>

#define L_SEQ 2048
#define H_CH  512
#define N_ST  64
#define BLK   1024  // threads per fftconv block (2 blocks/CU = 32 waves/CU)

__device__ __forceinline__ float frcp(float x) { return __builtin_amdgcn_rcpf(x); }
// float2-granular LDS pad for FFT buffers
#define A2(i) ((i) + ((i) >> 4))

// ---------------------------------------------------------------------------
// One radix-2^2 quad butterfly: two DIF stages fused in registers.
// ---------------------------------------------------------------------------
__device__ __forceinline__ void quad_bfly(float2* __restrict__ buf,
                                          const float2 w1, const float2 w2,
                                          float S, int e00, int e01, int e10, int e11)
{
    const float2 u0 = buf[e00], u1 = buf[e01];
    const float2 v0 = buf[e10], v1 = buf[e11];
    const float w1y = S * w1.y, w2y = S * w2.y;
    const float2 A = make_float2(u0.x + v0.x, u0.y + v0.y);
    const float2 C = make_float2(u1.x + v1.x, u1.y + v1.y);
    float dx = u0.x - v0.x, dy = u0.y - v0.y;
    const float2 B  = make_float2(dx * w1.x - dy * w1y, dx * w1y + dy * w1.x);
    dx = u1.x - v1.x;  dy = u1.y - v1.y;
    const float2 Dc = make_float2(dx * w1.x - dy * w1y, dx * w1y + dy * w1.x);
    const float2 D  = make_float2(-S * Dc.y, S * Dc.x);          // * iS
    buf[e00] = make_float2(A.x + C.x, A.y + C.y);
    dx = A.x - C.x;  dy = A.y - C.y;
    buf[e01] = make_float2(dx * w2.x - dy * w2y, dx * w2y + dy * w2.x);
    buf[e10] = make_float2(B.x + D.x, B.y + D.y);
    dx = B.x - D.x;  dy = B.y - D.y;
    buf[e11] = make_float2(dx * w2.x - dy * w2y, dx * w2y + dy * w2.x);
}

// ---------------------------------------------------------------------------
// Radix-2^2 DIF FFT in LDS: stages ST0..STEND-1 (lone leading radix-2 stage
// when the count is odd). Natural in, bit-reversed out (when STEND==LOGN).
// tw[A2(k)] = e^{+2pi i k/2048}. ssign=-1 fwd, +1 inv (unnormalized).
// ---------------------------------------------------------------------------
template<int LOGN, int ST0, int STEND>
__device__ __forceinline__ void fft4_lds(float2* buf, const float2* tw,
                                         int tid, float ssign)
{
    constexpr int N  = 1 << LOGN;
    constexpr int SH = 11 - LOGN;
    int st = ST0;
    if constexpr (((STEND - ST0) & 1) != 0) {
        const int H = (N >> 1) >> ST0;
        for (int b = tid; b < N / 2; b += BLK) {
            const int j  = b & (H - 1);
            const int i0 = ((b >> (LOGN - 1 - ST0)) << (LOGN - ST0)) + j;
            const int i1 = i0 + H;
            const float2 uu = buf[A2(i0)];
            const float2 vv = buf[A2(i1)];
            const float2 w  = tw[A2((j << ST0) << SH)];
            const float  wy = ssign * w.y;
            buf[A2(i0)] = make_float2(uu.x + vv.x, uu.y + vv.y);
            const float d0 = uu.x - vv.x, d1 = uu.y - vv.y;
            buf[A2(i1)] = make_float2(d0 * w.x - d1 * wy, d0 * wy + d1 * w.x);
        }
        __syncthreads();
        st = ST0 + 1;
    }
    for (; st < STEND; st += 2) {
        const int H  = (N >> 1) >> st;
        const int HQ = H >> 1;
        for (int q = tid; q < N / 4; q += BLK) {
            const int j   = q & (HQ - 1);
            const int blk = q >> (LOGN - 2 - st);
            const int i0  = (blk << (LOGN - st)) + j;
            quad_bfly(buf,
                      tw[A2((j << st) << SH)],
                      tw[A2((j << (st + 1)) << SH)],
                      ssign,
                      A2(i0), A2(i0 + HQ), A2(i0 + H), A2(i0 + H + HQ));
        }
        __syncthreads();
    }
}

// Dual: K- and U-FFTs under shared syncs, split across thread halves.
// Lone leading radix-2 stage when count odd (each half does 2 bflies).
template<int LOGN, int ST0, int STEND>
__device__ __forceinline__ void fft4_lds_dual(float2* bK, float2* bU,
                                              const float2* tw, int tid, float ssign)
{
    constexpr int N  = 1 << LOGN;
    constexpr int SH = 11 - LOGN;
    constexpr int NH = BLK / 2;            // 512
    static_assert(BLK == N / 2, "dual split needs BLK == N/2");
    float2* bb = (tid < NH) ? bK : bU;     // wave-uniform
    const int q = tid & (NH - 1);
    int st = ST0;
    if constexpr (((STEND - ST0) & 1) != 0) {
        const int H = (N >> 1) >> ST0;
#pragma unroll
        for (int bq = 0; bq < 2; ++bq) {
            const int b  = q + bq * NH;
            const int j  = b & (H - 1);
            const int i0 = ((b >> (LOGN - 1 - ST0)) << (LOGN - ST0)) + j;
            const int i1 = i0 + H;
            const float2 uu = bb[A2(i0)];
            const float2 vv = bb[A2(i1)];
            const float2 w  = tw[A2((j << ST0) << SH)];
            const float  wy = ssign * w.y;
            bb[A2(i0)] = make_float2(uu.x + vv.x, uu.y + vv.y);
            const float d0 = uu.x - vv.x, d1 = uu.y - vv.y;
            bb[A2(i1)] = make_float2(d0 * w.x - d1 * wy, d0 * wy + d1 * w.x);
        }
        __syncthreads();
        st = ST0 + 1;
    }
    for (; st < STEND; st += 2) {
        const int H  = (N >> 1) >> st;
        const int HQ = H >> 1;
        const int j   = q & (HQ - 1);
        const int blk = q >> (LOGN - 2 - st);
        const int i0  = (blk << (LOGN - st)) + j;
        quad_bfly(bb,
                  tw[A2((j << st) << SH)],
                  tw[A2((j << (st + 1)) << SH)],
                  ssign,
                  A2(i0), A2(i0 + HQ), A2(i0 + H), A2(i0 + H + HQ));
        __syncthreads();
    }
}

// ---------------------------------------------------------------------------
// Kernel 0: precompute per-(h,n) Cauchy weights into global scratch.
// ---------------------------------------------------------------------------
__global__ __launch_bounds__(256)
void s4_prep(const float* __restrict__ lam_r_g, const float* __restrict__ lam_i_g,
             const float* __restrict__ p_r_g,  const float* __restrict__ p_i_g,
             const float* __restrict__ b_r_g,  const float* __restrict__ b_i_g,
             const float* __restrict__ c_g,
             float4* __restrict__ Wa, float4* __restrict__ Wb, float* __restrict__ Wc)
{
    const int g = blockIdx.x * 256 + threadIdx.x;      // [0, 512*64)
    const float lr = fminf(lam_r_g[g], -0.0001f);
    const float li = lam_i_g[g];
    const float pr = p_r_g[g], pi = p_i_g[g];
    const float br = b_r_g[g], bi = b_i_g[g];
    const float c0 = c_g[2 * g], c1 = c_g[2 * g + 1];
    Wa[g] = make_float4(lr, li, c0 * br + c1 * bi, c0 * bi - c1 * br);
    Wb[g] = make_float4(c0 * pr + c1 * pi, c0 * pi - c1 * pr,
                        pr * br + pi * bi, pr * bi - pi * br);
    Wc[g] = pr * pr + pi * pi;
}

// ---------------------------------------------------------------------------
// Kernel 1: FUSED cauchy + spectral convolution, one block (1024 thr) per h.
// Boundary-stage fusions vs R17 (all twiddle-free, exact):
//  - 1024-pt iFFT skips its last stage; phase-2 pack combines (x0+-x1) in regs
//  - dual fwd FFT skips stage 10 (both buffers); phase 4 reconstructs bins
//    (m, m+1024) and mirrors from the two adjacent physical pairs
//  - phase-4 write fuses inverse stage 0; inverse FFT skips stage 10, done
//    in the epilogue from the adjacent pair
// ---------------------------------------------------------------------------
__global__ __launch_bounds__(BLK, 8)
void s4_fftconv(const float4* __restrict__ Wa, const float4* __restrict__ Wb,
                const float* __restrict__ Wc, const float* __restrict__ log_step_g,
                const float* __restrict__ u, float* __restrict__ Y)
{
    __shared__ float2 bufK[2175];   // A2(2047)=2174
    __shared__ float2 bufU[2175];   // first acts as roots scratch (natural idx)
    __shared__ float2 tw[1087];     // A2(1023)=1086
    const int h   = blockIdx.x;
    const int tid = threadIdx.x;    // [0, 1024)
    float2* __restrict__ rbuf = bufU;          // roots[0..2047], natural index

    // u prefetch first: HBM latency hides under the cauchy FMA phase
    const float uv0 = u[tid * H_CH + h];
    const float uv1 = u[(tid + 1024) * H_CH + h];

    {
        float sv, cv;
        sincosf((float)tid * (6.2831853071795864769f / 2048.0f), &sv, &cv);
        tw[A2(tid)] = make_float2(cv, sv);
    }

    // ---- phase 0: cauchy into LDS (2 points/thread: l = tid, tid+1024) ----
    const float step = expf(log_step_g[h]);
    const float ts   = 2.0f / step;
    const float4* __restrict__ wa = Wa + h * N_ST;
    const float4* __restrict__ wb = Wb + h * N_ST;
    const float*  __restrict__ wc = Wc + h * N_ST;

    {
        float grq[2], giq[2], c2rq[2], c2iq[2];
#pragma unroll
        for (int q = 0; q < 2; ++q) {
            const int l = tid + q * BLK;
            float wi, wr;
            sincosf(-6.2831853071795864769f * ((float)l * (1.0f / (float)L_SEQ)),
                    &wi, &wr);
            const float dr = 1.0f + wr, di = wi;
            const float dv = frcp(dr * dr + di * di);
            const float nr = 1.0f - wr, ni = -wi;
            grq[q]  = ts * (nr * dr + ni * di) * dv;
            giq[q]  = ts * (ni * dr - nr * di) * dv;
            c2rq[q] = 2.0f * dr * dv;
            c2iq[q] = -2.0f * di * dv;
        }
        float s00r[2] = {0,0}, s00i[2] = {0,0};
        float s01r[2] = {0,0}, s01i[2] = {0,0};
        float s10r[2] = {0,0}, s10i[2] = {0,0};
        float s11r[2] = {0,0}, s11i[2] = {0,0};
#pragma unroll 4
        for (int n = 0; n < N_ST; ++n) {
            const float4 A = wa[n];
            const float4 B = wb[n];
            const float w11 = wc[n];
#pragma unroll
            for (int q = 0; q < 2; ++q) {
                const float ddr = grq[q] - A.x;
                const float ddi = giq[q] - A.y;
                const float rinv = frcp(fmaf(ddr, ddr, ddi * ddi));
                const float rr = ddr * rinv;
                const float ri = -ddi * rinv;
                s00r[q] = fmaf(A.z, rr, fmaf(-A.w, ri, s00r[q]));
                s00i[q] = fmaf(A.z, ri, fmaf( A.w, rr, s00i[q]));
                s01r[q] = fmaf(B.x, rr, fmaf(-B.y, ri, s01r[q]));
                s01i[q] = fmaf(B.x, ri, fmaf( B.y, rr, s01i[q]));
                s10r[q] = fmaf(B.z, rr, fmaf(-B.w, ri, s10r[q]));
                s10i[q] = fmaf(B.z, ri, fmaf( B.w, rr, s10i[q]));
                s11r[q] = fmaf(w11, rr, s11r[q]);
                s11i[q] = fmaf(w11, ri, s11i[q]);
            }
        }
#pragma unroll
        for (int q = 0; q < 2; ++q) {
            const float qdr = 1.0f + s11r[q], qdi = s11i[q];
            const float qinv = frcp(qdr * qdr + qdi * qdi);
            const float pnr = s01r[q] * s10r[q] - s01i[q] * s10i[q];
            const float pni = s01r[q] * s10i[q] + s01i[q] * s10r[q];
            const float qr = (pnr * qdr + pni * qdi) * qinv;
            const float qi = (pni * qdr - pnr * qdi) * qinv;
            const float rr0 = s00r[q] - qr, ri0 = s00i[q] - qi;
            rbuf[tid + q * BLK] =
                make_float2(c2rq[q] * rr0 - c2iq[q] * ri0,
                            c2rq[q] * ri0 + c2iq[q] * rr0);
        }
    }

    __syncthreads();   // roots + tw visible

    // ---- phase 1: half-size irfft pack + 1024-pt inverse FFT (stages 0..8) ----
    {
        const int k = tid;              // [0,1024)
        float zr, zi;
        if (k == 0) {
            const float X0 = rbuf[0].x, XM = rbuf[1024].x;
            zr = X0 + XM;  zi = X0 - XM;
        } else {
            const float2 a  = rbuf[k],        b2 = rbuf[2048 - k];
            const float2 a2 = rbuf[1024 - k], b3 = rbuf[1024 + k];
            const float xkr = 0.5f * (a.x + b2.x),  xki = 0.5f * (a.y - b2.y);
            const float xmr = 0.5f * (a2.x + b3.x), xmi = -0.5f * (a2.y - b3.y);
            const float er = xkr + xmr, ei = xki + xmi;
            const float o_r = xkr - xmr, o_i = xki - xmi;
            const float2 w = tw[A2(k)];      // (cos, sin) of +2pi k/2048
            zr = er - fmaf(w.x, o_i,  w.y * o_r);
            zi = ei + fmaf(w.x, o_r, -w.y * o_i);
        }
        bufK[A2(k)] = make_float2(zr, zi);
    }
    __syncthreads();
    fft4_lds<10, 0, 9>(bufK, tw, tid, 1.0f);   // stage 9 fused into pack below

    // ---- phase 2+3: pack K (kern halves via reg-combined last stage) AND U,
    //      fused stage-0 (zero-pad), dual fwd FFT stages 1..9 ----
    float2 vk;
    {
        const int n0 = tid >> 1;                  // [0,512)
        const int e  = __brev(n0) >> 22;          // brev10(n0), even
        const float2 x0 = bufK[A2(e)];
        const float2 x1 = bufK[A2(e + 1)];
        // fused last stage of the 1024-pt iFFT (W=1): z[n0]=x0+x1, z[n0+512]=x0-x1
        const float zar = x0.x + x1.x, zai = x0.y + x1.y;
        const float zbr = x0.x - x1.x, zbi = x0.y - x1.y;
        const float k0v = ((tid & 1) ? zai : zar) * (1.0f / 2048.0f);
        const float k1v = ((tid & 1) ? zbi : zbr) * (1.0f / 2048.0f);
        vk = make_float2(k0v, k1v);
    }
    __syncthreads();
    {
        const int t = tid;
        const float2 w = tw[A2(t)];
        bufK[A2(t)] = vk;
        bufK[A2(t + 1024)] = make_float2(fmaf(vk.x, w.x,  vk.y * w.y),
                                         fmaf(vk.y, w.x, -vk.x * w.y));
        const float2 vu = make_float2(uv0, uv1);
        bufU[A2(t)] = vu;
        bufU[A2(t + 1024)] = make_float2(fmaf(vu.x, w.x,  vu.y * w.y),
                                         fmaf(vu.y, w.x, -vu.x * w.y));
    }
    __syncthreads();
    fft4_lds_dual<11, 1, 10>(bufK, bufU, tw, tid, -1.0f);  // stage 10 fused below

    // ---- phase 4: reconstruct bins from pre-stage-10 pairs, Hermitian unpack,
    //      pointwise product, write with fused inverse stage-0 ----
    float2 Rsum, Rdif;
    {
        const int e    = __brev(tid) >> 21;          // brev11(tid), even
        const int sMir = (1024 - tid) & 1023;
        const int ep   = __brev(sMir) >> 21;         // even
        const float2 kx0 = bufK[A2(e)],  kx1 = bufK[A2(e + 1)];
        const float2 ky0 = bufK[A2(ep)], ky1 = bufK[A2(ep + 1)];
        const float2 ux0 = bufU[A2(e)],  ux1 = bufU[A2(e + 1)];
        const float2 uy0 = bufU[A2(ep)], uy1 = bufU[A2(ep + 1)];
        // fused fwd stage 10 (W=1): bin m = x0+x1, bin m+1024 = x0-x1
        const float2 ZkM  = make_float2(kx0.x + kx1.x, kx0.y + kx1.y);  // tid
        const float2 ZkM1 = make_float2(kx0.x - kx1.x, kx0.y - kx1.y);  // tid+1024
        const float2 ZkS  = make_float2(ky0.x + ky1.x, ky0.y + ky1.y);  // sMir
        const float2 ZkS1 = make_float2(ky0.x - ky1.x, ky0.y - ky1.y);  // sMir+1024
        const float2 ZuM  = make_float2(ux0.x + ux1.x, ux0.y + ux1.y);
        const float2 ZuM1 = make_float2(ux0.x - ux1.x, ux0.y - ux1.y);
        const float2 ZuS  = make_float2(uy0.x + uy1.x, uy0.y + uy1.y);
        const float2 ZuS1 = make_float2(uy0.x - uy1.x, uy0.y - uy1.y);
        const bool self = (tid == 0);   // bins 0 and 1024 are self-mirrored

        float2 R[2];
#pragma unroll
        for (int q = 0; q < 2; ++q) {
            const float2 Zk  = q ? ZkM1 : ZkM;
            const float2 Zu  = q ? ZuM1 : ZuM;
            const float2 Zkp = self ? Zk : (q ? ZkS : ZkS1);
            const float2 Zup = self ? Zu : (q ? ZuS : ZuS1);
            const float F0r = 0.5f * (Zk.x + Zkp.x), F0i = 0.5f * (Zk.y - Zkp.y);
            const float F1r = 0.5f * (Zk.y + Zkp.y), F1i = 0.5f * (Zkp.x - Zk.x);
            const float U0r = 0.5f * (Zu.x + Zup.x), U0i = 0.5f * (Zu.y - Zup.y);
            const float U1r = 0.5f * (Zu.y + Zup.y), U1i = 0.5f * (Zup.x - Zu.x);
            const float Pr = F0r * U0r - F0i * U0i;
            const float Pi = F0r * U0i + F0i * U0r;
            const float Qr = F0r * U1r - F0i * U1i + F1r * U0r - F1i * U0i;
            const float Qi = F0r * U1i + F0i * U1r + F1r * U0i + F1i * U0r;
            R[q] = make_float2(Pr - Qi, Pi + Qr);      // R = P + iQ
        }
        Rsum = make_float2(R[0].x + R[1].x, R[0].y + R[1].y);
        Rdif = make_float2(R[0].x - R[1].x, R[0].y - R[1].y);
    }
    __syncthreads();   // all reads of bufK/bufU done before overwrite
    {
        // fused inverse stage 0 (bins tid, tid+1024; j = tid, ssign = +1)
        const float2 w = tw[A2(tid)];
        bufK[A2(tid)]        = Rsum;
        bufK[A2(tid + 1024)] = make_float2(Rdif.x * w.x - Rdif.y * w.y,
                                           Rdif.x * w.y + Rdif.y * w.x);
    }
    __syncthreads();
    fft4_lds<11, 1, 10>(bufK, tw, tid, 1.0f);  // stage 10 fused into epilogue

    // ---- phase 5: epilogue (fused inverse last stage, W=1) ----
    {
        const int e2 = __brev(tid) >> 21;          // brev11(tid), even
        const float2 x0 = bufK[A2(e2)];
        const float2 x1 = bufK[A2(e2 + 1)];
        const float rlx = x0.x + x1.x, rly = x0.y + x1.y;   // r[tid]
        const float rhx = x0.x - x1.x;                       // Re r[tid+1024]
        Y[h * 2048 + tid]        = rlx * (1.0f / 2048.0f);
        Y[h * 2048 + 1024 + tid] = (rhx + rly) * (1.0f / 2048.0f);
    }
}

// ---------------------------------------------------------------------------
// Kernel 2: finish = 64x64 LDS transpose + d*u add.
// ---------------------------------------------------------------------------
__global__ __launch_bounds__(256)
void s4_finish(const float* __restrict__ Y, const float* __restrict__ u,
               const float* __restrict__ dvec, float* __restrict__ out)
{
    __shared__ float tile[64][65];
    const int t0   = blockIdx.x * 64;
    const int h0   = blockIdx.y * 64;
    const int lane = threadIdx.x & 63;
    const int rowg = threadIdx.x >> 6;         // 0..3

#pragma unroll
    for (int rr = 0; rr < 16; ++rr) {
        const int hr = rowg * 16 + rr;
        tile[hr][lane] = Y[(h0 + hr) * 2048 + t0 + lane];
    }
    __syncthreads();

    const float dh = dvec[h0 + lane];
#pragma unroll
    for (int rr = 0; rr < 16; ++rr) {
        const int tr = rowg * 16 + rr;
        const int t  = t0 + tr;
        out[t * H_CH + h0 + lane] =
            fmaf(dh, u[t * H_CH + h0 + lane], tile[lane][tr]);
    }
}

// ---------------------------------------------------------------------------
extern "C" void kernel_launch(void* const* d_in, const int* in_sizes, int n_in,
                              void* d_out, int out_size, void* d_ws, size_t ws_size,
                              hipStream_t stream)
{
    const float* u        = (const float*)d_in[0];
    const float* lam_r    = (const float*)d_in[1];
    const float* lam_i    = (const float*)d_in[2];
    const float* p_r      = (const float*)d_in[3];
    const float* p_i      = (const float*)d_in[4];
    const float* b_r      = (const float*)d_in[5];
    const float* b_i      = (const float*)d_in[6];
    const float* cmat     = (const float*)d_in[7];
    const float* dvec     = (const float*)d_in[8];
    const float* log_step = (const float*)d_in[9];
    float* out = (float*)d_out;

    char* ws = (char*)d_ws;
    float*  Y     = (float*)(ws + (size_t)8 * 1024 * 1024);   // 4 MB @ 8M
    float4* Wa    = (float4*)(ws + (size_t)12 * 1024 * 1024); // 512 KB
    float4* Wb    = (float4*)(ws + (size_t)12 * 1024 * 1024 + 512 * 1024);
    float*  Wc    = (float*) (ws + (size_t)13 * 1024 * 1024); // 128 KB

    s4_prep<<<dim3(H_CH * N_ST / 256), dim3(256), 0, stream>>>(
        lam_r, lam_i, p_r, p_i, b_r, b_i, cmat, Wa, Wb, Wc);
    s4_fftconv<<<dim3(H_CH), dim3(BLK), 0, stream>>>(
        Wa, Wb, Wc, log_step, u, Y);
    s4_finish<<<dim3(L_SEQ / 64, H_CH / 64), dim3(256), 0, stream>>>(
        Y, u, dvec, out);
}